// Round 9
// baseline (505.287 us; speedup 1.0000x reference)
//
#include <hip/hip_runtime.h>

#define DI __device__ __forceinline__
#define NSAMP 65536

typedef __attribute__((ext_vector_type(4))) float f32x4;
typedef __attribute__((ext_vector_type(8))) short short8;
typedef __attribute__((ext_vector_type(4))) short short4v;

DI float frcp(float x){ return __builtin_amdgcn_rcpf(x); }
DI float frsq(float x){ return __builtin_amdgcn_rsqf(x); }
DI float sigmf(float x){ return frcp(1.f + __expf(-x)); }
DI float tanhf_(float x){ return 1.f - 2.f*frcp(__expf(2.f*x) + 1.f); }
DI unsigned short f2bf(float f){                 // RNE float->bf16
  unsigned u = __float_as_uint(f);
  return (unsigned short)((u + 0x7FFFu + ((u>>16)&1u)) >> 16);
}

struct Params {
  const float* __restrict__ x;
  const float* __restrict__ pv;    // [6][NSAMP] (ws)
  const float* __restrict__ ptail; // gathered small params [1518] (ws)
  const unsigned short* __restrict__ frags;
  const float* __restrict__ Wih0; const float* __restrict__ Whh0;
  const float* __restrict__ bih0; const float* __restrict__ bhh0;
  const float* __restrict__ Wih1; const float* __restrict__ Whh1;
  const float* __restrict__ bih1; const float* __restrict__ bhh1;
  const float* __restrict__ fcW;  const float* __restrict__ fcb;
  const float* __restrict__ W2;   const float* __restrict__ b2;
  const float* __restrict__ g2;   const float* __restrict__ be2;
  const float* __restrict__ W3;   const float* __restrict__ b3;
  const float* __restrict__ g3;   const float* __restrict__ be3;
  const float* __restrict__ W1f;  const float* __restrict__ b1f;
  const float* __restrict__ g1f;  const float* __restrict__ be1f;
  const float* __restrict__ W2f;  const float* __restrict__ b2f;
  const float* __restrict__ g2f;  const float* __restrict__ be2f;
  const float* __restrict__ W3f;  const float* __restrict__ b3f;
  const float* __restrict__ g3f;  const float* __restrict__ be3f;
  float* __restrict__ out;
};

// ptail offsets (floats)
#define PT_G2   0
#define PT_BE2  408
#define PT_G3   816
#define PT_BE3  918
#define PT_B1F  1020
#define PT_G1F  1052
#define PT_BE1F 1084
#define PT_B2F  1116
#define PT_G2F  1148
#define PT_BE2F 1180
#define PT_B3F  1212
#define PT_G3F  1314
#define PT_BE3F 1416
#define PT_N    1518
#define NFRAG   49

// ---------- prep: all weight B-fragments (bf16) + bias sums + param gather ----------
// B-frag layout (mfma_f32_16x16x32_bf16): lane l holds B[k][n], n=16*tile+(l&15);
// elems j=0..3 -> k=4*(l>>4)+j, j=4..7 -> k=16+4*(l>>4)+j   (verified via lstm)
__global__ __launch_bounds__(256,1) void prep_kernel(Params p,
    unsigned short* __restrict__ frags, float* __restrict__ bsum,
    float* __restrict__ ptail){
  const int tid = threadIdx.x;
  if(tid < 64){
    const int l15 = tid & 15, g4 = tid >> 4;
    // lstm mats: 0=Whh0, 1=Wih1, 2=Whh1 ([128][32]); 3=Wih0 (K=3 pad 32)
    const float* mats[3] = {p.Whh0, p.Wih1, p.Whh1};
    for(int m=0;m<3;m++)
      for(int t=0;t<8;t++){
        const int n = 16*t + l15;
        unsigned short* dst = &frags[((size_t)(m*8+t)*64 + tid)*8];
        for(int j=0;j<4;j++){
          dst[j]   = f2bf(mats[m][n*32 + 4*g4 + j]);
          dst[4+j] = f2bf(mats[m][n*32 + 16 + 4*g4 + j]);
        }
      }
    for(int t=0;t<8;t++){
      const int n = 16*t + l15;
      unsigned short* dst = &frags[((size_t)(24+t)*64 + tid)*8];
      for(int j=0;j<4;j++){
        int k = 4*g4 + j;
        dst[j]   = (k < 3) ? f2bf(p.Wih0[n*3 + k]) : (unsigned short)0;
        dst[4+j] = 0;
      }
    }
    // f1: [108pad128][32] from W1f[32][108] -> idx 32 + kc*2 + nt
    for(int kc=0;kc<4;kc++)
      for(int nt=0;nt<2;nt++){
        const int n = nt*16 + l15;
        unsigned short* dst = &frags[((size_t)(32+kc*2+nt)*64 + tid)*8];
        for(int j=0;j<4;j++){
          int k0 = kc*32 + 4*g4 + j;
          int k1 = kc*32 + 16 + 4*g4 + j;
          dst[j]   = (k0<108) ? f2bf(p.W1f[n*108+k0]) : (unsigned short)0;
          dst[4+j] = (k1<108) ? f2bf(p.W1f[n*108+k1]) : (unsigned short)0;
        }
      }
    // f2: [32][32] from W2f -> idx 40+nt
    for(int nt=0;nt<2;nt++){
      const int n = nt*16 + l15;
      unsigned short* dst = &frags[((size_t)(40+nt)*64 + tid)*8];
      for(int j=0;j<4;j++){
        dst[j]   = f2bf(p.W2f[n*32 + 4*g4 + j]);
        dst[4+j] = f2bf(p.W2f[n*32 + 16 + 4*g4 + j]);
      }
    }
    // f3: [32][102pad112] from W3f[102][32] -> idx 42+nt (7 tiles)
    for(int nt=0;nt<7;nt++){
      const int n2 = nt*16 + l15;
      unsigned short* dst = &frags[((size_t)(42+nt)*64 + tid)*8];
      for(int j=0;j<4;j++){
        int k0 = 4*g4 + j, k1 = 16 + 4*g4 + j;
        dst[j]   = (n2<102) ? f2bf(p.W3f[n2*32+k0]) : (unsigned short)0;
        dst[4+j] = (n2<102) ? f2bf(p.W3f[n2*32+k1]) : (unsigned short)0;
      }
    }
  } else if(tid < 192){
    int i = tid - 64;
    bsum[i]       = p.bih0[i] + p.bhh0[i];
    bsum[128 + i] = p.bih1[i] + p.bhh1[i];
  }
  // gather small params
  for(int i=tid;i<408;i+=256){ ptail[PT_G2+i]=p.g2[i]; ptail[PT_BE2+i]=p.be2[i]; }
  for(int i=tid;i<102;i+=256){
    ptail[PT_G3+i]=p.g3[i];   ptail[PT_BE3+i]=p.be3[i];
    ptail[PT_B3F+i]=p.b3f[i]; ptail[PT_G3F+i]=p.g3f[i]; ptail[PT_BE3F+i]=p.be3f[i];
  }
  if(tid<32){
    ptail[PT_B1F+tid]=p.b1f[tid];   ptail[PT_G1F+tid]=p.g1f[tid];
    ptail[PT_BE1F+tid]=p.be1f[tid]; ptail[PT_B2F+tid]=p.b2f[tid];
    ptail[PT_G2F+tid]=p.g2f[tid];   ptail[PT_BE2F+tid]=p.be2f[tid];
  }
}

// A-frag from fp32 LDS (lstm h-buffer [16][36])
DI short8 mk_afrag(const float* hbase, int l15, int g4){
  const float4* p0 = (const float4*)(hbase + l15*36 + 4*g4);
  const float4* p1 = (const float4*)(hbase + l15*36 + 16 + 4*g4);
  float4 lo = *p0; float4 hi = *p1;
  short8 s;
  s[0]=(short)f2bf(lo.x); s[1]=(short)f2bf(lo.y); s[2]=(short)f2bf(lo.z); s[3]=(short)f2bf(lo.w);
  s[4]=(short)f2bf(hi.x); s[5]=(short)f2bf(hi.y); s[6]=(short)f2bf(hi.z); s[7]=(short)f2bf(hi.w);
  return s;
}
// A-frag from bf16 LDS, element offset off (8 values: off..off+3, off+16..off+19)
DI short8 mk_af16(const unsigned short* lb, int off){
  short4v lo = *(const short4v*)(lb + off);
  short4v hi = *(const short4v*)(lb + off + 16);
  short8 s;
  s[0]=lo[0]; s[1]=lo[1]; s[2]=lo[2]; s[3]=lo[3];
  s[4]=hi[0]; s[5]=hi[1]; s[6]=hi[2]; s[7]=hi[3];
  return s;
}
DI short8 mk_af16_lo(const unsigned short* lb, int off){  // hi half = 0
  short4v lo = *(const short4v*)(lb + off);
  short8 s;
  s[0]=lo[0]; s[1]=lo[1]; s[2]=lo[2]; s[3]=lo[3];
  s[4]=0; s[5]=0; s[6]=0; s[7]=0;
  return s;
}

// ---------- LSTM via MFMA: 1 wave = 16 samples (unchanged, proven) ----------
__global__ __launch_bounds__(256,1) void lstm_kernel(
    const float* __restrict__ x, const unsigned short* __restrict__ frags,
    const float* __restrict__ bsum, const float* __restrict__ fcW,
    const float* __restrict__ fcb, float* __restrict__ pv){
  __shared__ float hb[4][2][16][36];
  const int tid = threadIdx.x;
  const int w = tid >> 6, l = tid & 63;
  const int l15 = l & 15, g4 = l >> 4;
  const int base = blockIdx.x*64 + w*16;
  const float* __restrict__ xrow = x + (size_t)(base + l15)*348;

  short8 wf[4][8];
  const short8* fsrc = (const short8*)frags;
  #pragma unroll
  for(int m=0;m<4;m++)
    #pragma unroll
    for(int t=0;t<8;t++) wf[m][t] = fsrc[(m*8+t)*64 + l];

  float bfr[2][8];
  #pragma unroll
  for(int t=0;t<8;t++){
    bfr[0][t] = bsum[16*t + l15];
    bfr[1][t] = bsum[128 + 16*t + l15];
  }
  #pragma unroll
  for(int half=0; half<2; half++)
    #pragma unroll
    for(int r=0;r<4;r++){
      hb[w][0][g4*4+r][l15+16*half] = 0.f;
      hb[w][1][g4*4+r][l15+16*half] = 0.f;
    }
  float c0[8], c1[8];
  #pragma unroll
  for(int i=0;i<8;i++){ c0[i]=0.f; c1[i]=0.f; }

  #pragma unroll 1
  for(int t=0;t<4;t++){
    short8 ax;
    {
      float xv0 = xrow[220 + t*3 + 0];
      float xv1 = xrow[220 + t*3 + 1];
      float xv2 = xrow[220 + t*3 + 2];
      bool gz = (g4 == 0);
      ax[0] = gz ? (short)f2bf(xv0) : (short)0;
      ax[1] = gz ? (short)f2bf(xv1) : (short)0;
      ax[2] = gz ? (short)f2bf(xv2) : (short)0;
      ax[3]=0; ax[4]=0; ax[5]=0; ax[6]=0; ax[7]=0;
    }
    short8 ah0 = mk_afrag(&hb[w][0][0][0], l15, g4);
    f32x4 acc0[8];
    #pragma unroll
    for(int n=0;n<8;n++){
      f32x4 a; a[0]=bfr[0][n]; a[1]=bfr[0][n]; a[2]=bfr[0][n]; a[3]=bfr[0][n];
      a = __builtin_amdgcn_mfma_f32_16x16x32_bf16(ax,  wf[3][n], a, 0,0,0);
      a = __builtin_amdgcn_mfma_f32_16x16x32_bf16(ah0, wf[0][n], a, 0,0,0);
      acc0[n] = a;
    }
    #pragma unroll
    for(int half=0; half<2; half++)
      #pragma unroll
      for(int r=0;r<4;r++){
        float gi = acc0[0+half][r], gf = acc0[2+half][r];
        float gg = acc0[4+half][r], go = acc0[6+half][r];
        float cc = sigmf(gf)*c0[half*4+r] + sigmf(gi)*tanhf_(gg);
        c0[half*4+r] = cc;
        hb[w][0][g4*4+r][l15+16*half] = sigmf(go)*tanhf_(cc);
      }
    short8 ah0n = mk_afrag(&hb[w][0][0][0], l15, g4);
    short8 ah1  = mk_afrag(&hb[w][1][0][0], l15, g4);
    f32x4 acc1[8];
    #pragma unroll
    for(int n=0;n<8;n++){
      f32x4 a; a[0]=bfr[1][n]; a[1]=bfr[1][n]; a[2]=bfr[1][n]; a[3]=bfr[1][n];
      a = __builtin_amdgcn_mfma_f32_16x16x32_bf16(ah0n, wf[1][n], a, 0,0,0);
      a = __builtin_amdgcn_mfma_f32_16x16x32_bf16(ah1,  wf[2][n], a, 0,0,0);
      acc1[n] = a;
    }
    #pragma unroll
    for(int half=0; half<2; half++)
      #pragma unroll
      for(int r=0;r<4;r++){
        float gi = acc1[0+half][r], gf = acc1[2+half][r];
        float gg = acc1[4+half][r], go = acc1[6+half][r];
        float cc = sigmf(gf)*c1[half*4+r] + sigmf(gi)*tanhf_(gg);
        c1[half*4+r] = cc;
        hb[w][1][g4*4+r][l15+16*half] = sigmf(go)*tanhf_(cc);
      }
  }
  if(l < 16){
    const int gs = base + l;
    const float* xr2 = x + (size_t)gs*348;
    #pragma unroll
    for(int d=0;d<3;d++){
      float a = fcb[d];
      #pragma unroll
      for(int u=0;u<32;u++) a += hb[w][1][l][u]*fcW[d*32+u];
      float pr = xr2[229 + d];
      pv[(size_t)d*NSAMP + gs]     = a;
      pv[(size_t)(3+d)*NSAMP + gs] = (a - pr)*10.f;
    }
  }
}

DI float rg4(float v){       // reduce across the 4 g4 groups (same l15)
  v += __shfl_xor(v, 16);
  v += __shfl_xor(v, 32);
  return v;
}

// ---------- tail: conv (scalar) + f1/f2/f3 via MFMA. 1 wave = 16 samples ----------
__global__ __launch_bounds__(256,1) void tail_kernel(Params p){
  __shared__ float prm[PT_N];
  __shared__ __align__(16) unsigned short lb16[4][16*116];
  const int tid = threadIdx.x;
  for(int i=tid;i<PT_N;i+=256) prm[i]=p.ptail[i];
  const int w = tid >> 6, l = tid & 63;
  const int l15 = l & 15, g4 = l >> 4;
  const int base = blockIdx.x*64 + w*16;
  unsigned short* lb = &lb16[w][0];
  const short8* fsrc = (const short8*)p.frags;

  // pp/vel into slots 102..107 (raw bf16), zero 108..115
  if(l < 16){
    #pragma unroll
    for(int d=0;d<3;d++){
      lb[l*116+102+d] = f2bf(p.pv[(size_t)d*NSAMP + base + l]);
      lb[l*116+105+d] = f2bf(p.pv[(size_t)(3+d)*NSAMP + base + l]);
    }
    #pragma unroll
    for(int k=108;k<116;k++) lb[l*116+k] = 0;
  }
  __syncthreads();                       // prm ready (lb traffic is wave-internal)

  // ---- conv: sample base+l15, cols C0..C0+25 ----
  const float* __restrict__ xr = p.x + (size_t)(base+l15)*348;
  const int C0   = g4*26;
  const int ncol = (g4==3) ? 24 : 26;

  // pass 1: LN2 stats
  float s1=0.f, s2=0.f;
  {
    float u0[3],u1[3],u2[3],u3[3],u4[3];
    #pragma unroll
    for(int r=0;r<3;r++){
      u0[r] = (C0-2 >= 0) ? xr[r*116 + 1 + C0-2] : 0.f;
      u1[r] = (C0-1 >= 0) ? xr[r*116 + 1 + C0-1] : 0.f;
      u2[r] = xr[r*116 + 1 + C0];
      u3[r] = xr[r*116 + 1 + C0+1];
      u4[r] = xr[r*116 + 1 + C0+2];
    }
    #pragma unroll 2
    for(int i=0;i<26;i++){
      float msk = (i < ncol) ? 1.f : 0.f;
      #pragma unroll
      for(int o=0;o<4;o++){
        float sv = p.b2[o];
        #pragma unroll
        for(int r=0;r<3;r++)
          sv += u0[r]*p.W2[o*15+r*5+0]+u1[r]*p.W2[o*15+r*5+1]+u2[r]*p.W2[o*15+r*5+2]
              + u3[r]*p.W2[o*15+r*5+3]+u4[r]*p.W2[o*15+r*5+4];
        s1 += msk*sv; s2 += msk*sv*sv;
      }
      int pn = C0 + i + 3;
      int pc = (pn <= 101) ? pn : 101;
      #pragma unroll
      for(int r=0;r<3;r++){
        float nv = xr[r*116 + 1 + pc];
        nv = (pn <= 101) ? nv : 0.f;
        u0[r]=u1[r]; u1[r]=u2[r]; u2[r]=u3[r]; u3[r]=u4[r]; u4[r]=nv;
      }
    }
  }
  float m2  = rg4(s1)*(1.f/408.f);
  float va2 = rg4(s2)*(1.f/408.f) - m2*m2;
  float rs2 = frsq(va2 + 1e-5f);

  // pass 2: recompute + LN2/relu + cv3 -> o3r[26] (regs), then LN3 stats
  float o3r[26];
  float s31=0.f, s32=0.f;
  {
    float u0[3],u1[3],u2[3],u3[3],u4[3];
    #pragma unroll
    for(int r=0;r<3;r++){
      u0[r] = (C0-2 >= 0) ? xr[r*116 + 1 + C0-2] : 0.f;
      u1[r] = (C0-1 >= 0) ? xr[r*116 + 1 + C0-1] : 0.f;
      u2[r] = xr[r*116 + 1 + C0];
      u3[r] = xr[r*116 + 1 + C0+1];
      u4[r] = xr[r*116 + 1 + C0+2];
    }
    #pragma unroll 2
    for(int i=0;i<26;i++){
      const int wc = (C0+i <= 101) ? C0+i : 101;
      float msk = (i < ncol) ? 1.f : 0.f;
      float o3 = p.b3[0];
      #pragma unroll
      for(int o=0;o<4;o++){
        float sv = p.b2[o];
        #pragma unroll
        for(int r=0;r<3;r++)
          sv += u0[r]*p.W2[o*15+r*5+0]+u1[r]*p.W2[o*15+r*5+1]+u2[r]*p.W2[o*15+r*5+2]
              + u3[r]*p.W2[o*15+r*5+3]+u4[r]*p.W2[o*15+r*5+4];
        float nv = (sv - m2)*rs2*prm[PT_G2+o*102+wc] + prm[PT_BE2+o*102+wc];
        o3 += fmaxf(nv, 0.f)*p.W3[o];
      }
      s31 += msk*o3; s32 += msk*o3*o3;
      o3r[i] = o3;
      int pn = C0 + i + 3;
      int pc = (pn <= 101) ? pn : 101;
      #pragma unroll
      for(int r=0;r<3;r++){
        float nv = xr[r*116 + 1 + pc];
        nv = (pn <= 101) ? nv : 0.f;
        u0[r]=u1[r]; u1[r]=u2[r]; u2[r]=u3[r]; u3[r]=u4[r]; u4[r]=nv;
      }
    }
  }
  float m3  = rg4(s31)*(1.f/102.f);
  float va3 = rg4(s32)*(1.f/102.f) - m3*m3;
  float rs3 = frsq(va3 + 1e-5f);

  // LN3 + relu, write bf16 to lb[sample=l15][col]
  #pragma unroll
  for(int i=0;i<26;i++){
    if(i < ncol){
      const int wc = C0 + i;
      float v = fmaxf((o3r[i]-m3)*rs3*prm[PT_G3+wc] + prm[PT_BE3+wc], 0.f);
      lb[l15*116 + wc] = f2bf(v);
    }
  }

  // ---- f1: [16 x 108pad128] @ [128 x 32] = 8 MFMA ----
  f32x4 a1acc[2];
  {
    float b0v = prm[PT_B1F + l15], b1v = prm[PT_B1F + 16 + l15];
    a1acc[0] = f32x4{b0v,b0v,b0v,b0v};
    a1acc[1] = f32x4{b1v,b1v,b1v,b1v};
  }
  #pragma unroll
  for(int kc=0;kc<4;kc++){
    short8 af = (kc<3) ? mk_af16(lb, l15*116 + kc*32 + 4*g4)
                       : mk_af16_lo(lb, l15*116 + 96 + 4*g4);
    #pragma unroll
    for(int nt=0;nt<2;nt++){
      short8 bf = fsrc[(32+kc*2+nt)*64 + l];
      a1acc[nt] = __builtin_amdgcn_mfma_f32_16x16x32_bf16(af, bf, a1acc[nt], 0,0,0);
    }
  }
  // LN1 per sample row (4g4+r): reduce over 16 l15-lanes x 2 tiles
  {
    float m1[4], rs1[4];
    #pragma unroll
    for(int r=0;r<4;r++){
      float sm = a1acc[0][r] + a1acc[1][r];
      float sq = a1acc[0][r]*a1acc[0][r] + a1acc[1][r]*a1acc[1][r];
      #pragma unroll
      for(int st=1;st<16;st<<=1){ sm += __shfl_xor(sm,st); sq += __shfl_xor(sq,st); }
      float m = sm*(1.f/32.f);
      m1[r]=m; rs1[r]=frsq(sq*(1.f/32.f)-m*m+1e-5f);
    }
    #pragma unroll
    for(int nt=0;nt<2;nt++){
      float g  = prm[PT_G1F + nt*16 + l15];
      float be = prm[PT_BE1F + nt*16 + l15];
      #pragma unroll
      for(int r=0;r<4;r++){
        float vv = fmaxf((a1acc[nt][r]-m1[r])*rs1[r]*g + be, 0.f);
        lb[(4*g4+r)*116 + nt*16 + l15] = f2bf(vv);
      }
    }
  }

  // ---- f2: [16 x 32] @ [32 x 32] = 2 MFMA ----
  f32x4 a2acc[2];
  {
    float b0v = prm[PT_B2F + l15], b1v = prm[PT_B2F + 16 + l15];
    a2acc[0] = f32x4{b0v,b0v,b0v,b0v};
    a2acc[1] = f32x4{b1v,b1v,b1v,b1v};
    short8 af = mk_af16(lb, l15*116 + 4*g4);
    #pragma unroll
    for(int nt=0;nt<2;nt++){
      short8 bf = fsrc[(40+nt)*64 + l];
      a2acc[nt] = __builtin_amdgcn_mfma_f32_16x16x32_bf16(af, bf, a2acc[nt], 0,0,0);
    }
    float m1[4], rs1[4];
    #pragma unroll
    for(int r=0;r<4;r++){
      float sm = a2acc[0][r] + a2acc[1][r];
      float sq = a2acc[0][r]*a2acc[0][r] + a2acc[1][r]*a2acc[1][r];
      #pragma unroll
      for(int st=1;st<16;st<<=1){ sm += __shfl_xor(sm,st); sq += __shfl_xor(sq,st); }
      float m = sm*(1.f/32.f);
      m1[r]=m; rs1[r]=frsq(sq*(1.f/32.f)-m*m+1e-5f);
    }
    #pragma unroll
    for(int nt=0;nt<2;nt++){
      float g  = prm[PT_G2F + nt*16 + l15];
      float be = prm[PT_BE2F + nt*16 + l15];
      #pragma unroll
      for(int r=0;r<4;r++){
        float vv = fmaxf((a2acc[nt][r]-m1[r])*rs1[r]*g + be, 0.f);
        lb[(4*g4+r)*116 + nt*16 + l15] = f2bf(vv);
      }
    }
  }

  // ---- f3: [16 x 32] @ [32 x 102pad112] = 7 MFMA ----
  {
    f32x4 a3[7];
    float mskt[7];
    #pragma unroll
    for(int nt=0;nt<7;nt++){
      int n2 = nt*16 + l15;
      mskt[nt] = (n2 < 102) ? 1.f : 0.f;
      float bv = prm[PT_B3F + ((n2<102)?n2:0)] * mskt[nt];
      a3[nt] = f32x4{bv,bv,bv,bv};
    }
    short8 af = mk_af16(lb, l15*116 + 4*g4);
    #pragma unroll
    for(int nt=0;nt<7;nt++){
      short8 bf = fsrc[(42+nt)*64 + l];
      a3[nt] = __builtin_amdgcn_mfma_f32_16x16x32_bf16(af, bf, a3[nt], 0,0,0);
    }
    float mf[4], rsf[4];
    #pragma unroll
    for(int r=0;r<4;r++){
      float sm=0.f, sq=0.f;
      #pragma unroll
      for(int nt=0;nt<7;nt++){
        float vv = a3[nt][r];
        sm += mskt[nt]*vv; sq += mskt[nt]*vv*vv;
      }
      #pragma unroll
      for(int st=1;st<16;st<<=1){ sm += __shfl_xor(sm,st); sq += __shfl_xor(sq,st); }
      float m = sm*(1.f/102.f);
      mf[r]=m; rsf[r]=frsq(sq*(1.f/102.f)-m*m+1e-5f);
    }
    #pragma unroll
    for(int nt=0;nt<7;nt++){
      int n2 = nt*16 + l15;
      if(n2 < 102){
        float g  = prm[PT_G3F + n2];
        float be = prm[PT_BE3F + n2];
        #pragma unroll
        for(int r=0;r<4;r++){
          float val = sigmf((a3[nt][r]-mf[r])*rsf[r]*g + be);
          p.out[(size_t)(base + 4*g4 + r)*102 + n2] = val;
        }
      }
    }
  }
}

// ---------- AoS monolithic fallback (R1, proven) ----------
template<int IN>
DI void lstm_step(const float* __restrict__ Wih, const float* __restrict__ Whh,
                  const float* __restrict__ bih, const float* __restrict__ bhh,
                  const float* xin, const float* hin, float* c, float* hout){
  #pragma unroll
  for(int j=0;j<32;j++){
    float ai = bih[j]    + bhh[j];
    float af = bih[32+j] + bhh[32+j];
    float ag = bih[64+j] + bhh[64+j];
    float ao = bih[96+j] + bhh[96+j];
    #pragma unroll
    for(int k=0;k<IN;k++){
      float xv = xin[k];
      ai += xv*Wih[j*IN+k]; af += xv*Wih[(32+j)*IN+k];
      ag += xv*Wih[(64+j)*IN+k]; ao += xv*Wih[(96+j)*IN+k];
    }
    #pragma unroll
    for(int k=0;k<32;k++){
      float hv = hin[k];
      ai += hv*Whh[j*32+k]; af += hv*Whh[(32+j)*32+k];
      ag += hv*Whh[(64+j)*32+k]; ao += hv*Whh[(96+j)*32+k];
    }
    float cc = sigmf(af)*c[j] + sigmf(ai)*tanhf_(ag);
    c[j] = cc;
    hout[j] = sigmf(ao)*tanhf_(cc);
  }
}

__global__ __launch_bounds__(128,1) void csnet_mono(Params p){
  const int tid = threadIdx.x;
  const int b = blockIdx.x*128 + tid;
  const float* __restrict__ xr = p.x + (size_t)b*348;
  __shared__ float sbuf[128*103];
  float* my = &sbuf[tid*103];
  float h0[32], c0[32], h1[32], c1[32];
  #pragma unroll
  for(int j=0;j<32;j++){ h0[j]=0.f; c0[j]=0.f; h1[j]=0.f; c1[j]=0.f; }
  #pragma unroll 1
  for(int t=0;t<4;t++){
    float xt[3];
    #pragma unroll
    for(int d=0;d<3;d++) xt[d] = xr[220 + t*3 + d];
    float hA[32], hB[32];
    lstm_step<3 >(p.Wih0,p.Whh0,p.bih0,p.bhh0, xt, h0, c0, hA);
    lstm_step<32>(p.Wih1,p.Whh1,p.bih1,p.bhh1, hA, h1, c1, hB);
    #pragma unroll
    for(int j=0;j<32;j++){ h0[j]=hA[j]; h1[j]=hB[j]; }
  }
  float pp[3], vel[3];
  #pragma unroll
  for(int d=0;d<3;d++){
    float a = p.fcb[d];
    #pragma unroll
    for(int j=0;j<32;j++) a += h1[j]*p.fcW[d*32+j];
    pp[d]  = a;
    vel[d] = (a - xr[229+d])*10.f;
  }
  float s1 = 0.f, s2 = 0.f;
  for(int w=0; w<102; ++w){
    #pragma unroll
    for(int o=0;o<4;o++){
      float s = p.b2[o];
      #pragma unroll
      for(int r=0;r<3;r++)
        #pragma unroll
        for(int kk=0;kk<5;kk++){
          int c = w - 2 + kk;
          float v = (c>=0 && c<=101) ? xr[r*116 + 1 + (c<0?0:(c>101?101:c))] : 0.f;
          s += v*p.W2[o*15 + r*5 + kk];
        }
      s1 += s; s2 += s*s;
    }
  }
  float m2  = s1*(1.f/408.f);
  float rs2 = frsq(s2*(1.f/408.f) - m2*m2 + 1e-5f);
  float s31=0.f, s32=0.f;
  for(int w=0; w<102; ++w){
    float o3 = p.b3[0];
    #pragma unroll
    for(int o=0;o<4;o++){
      float s = p.b2[o];
      #pragma unroll
      for(int r=0;r<3;r++)
        #pragma unroll
        for(int kk=0;kk<5;kk++){
          int c = w - 2 + kk;
          float v = (c>=0 && c<=101) ? xr[r*116 + 1 + (c<0?0:(c>101?101:c))] : 0.f;
          s += v*p.W2[o*15 + r*5 + kk];
        }
      float nv = (s - m2)*rs2*p.g2[o*102+w] + p.be2[o*102+w];
      o3 += fmaxf(nv, 0.f)*p.W3[o];
    }
    s31 += o3; s32 += o3*o3;
    my[w] = o3;
  }
  float m3  = s31*(1.f/102.f);
  float rs3 = frsq(s32*(1.f/102.f) - m3*m3 + 1e-5f);
  float a1[32];
  #pragma unroll
  for(int j=0;j<32;j++) a1[j] = p.b1f[j];
  for(int w=0; w<102; ++w){
    float v = fmaxf((my[w]-m3)*rs3*p.g3[w] + p.be3[w], 0.f);
    #pragma unroll
    for(int j=0;j<32;j++) a1[j] += v*p.W1f[j*108+w];
  }
  #pragma unroll
  for(int d=0;d<3;d++)
    #pragma unroll
    for(int j=0;j<32;j++){
      a1[j] += pp[d]*p.W1f[j*108+102+d];
      a1[j] += vel[d]*p.W1f[j*108+105+d];
    }
  {
    float s=0.f,qq=0.f;
    #pragma unroll
    for(int j=0;j<32;j++){ s+=a1[j]; qq+=a1[j]*a1[j]; }
    float m=s*(1.f/32.f), rs=frsq(qq*(1.f/32.f)-m*m+1e-5f);
    #pragma unroll
    for(int j=0;j<32;j++) a1[j]=fmaxf((a1[j]-m)*rs*p.g1f[j]+p.be1f[j],0.f);
  }
  float a2[32];
  #pragma unroll
  for(int j=0;j<32;j++){
    float a = p.b2f[j];
    #pragma unroll
    for(int k=0;k<32;k++) a += a1[k]*p.W2f[j*32+k];
    a2[j]=a;
  }
  {
    float s=0.f,qq=0.f;
    #pragma unroll
    for(int j=0;j<32;j++){ s+=a2[j]; qq+=a2[j]*a2[j]; }
    float m=s*(1.f/32.f), rs=frsq(qq*(1.f/32.f)-m*m+1e-5f);
    #pragma unroll
    for(int j=0;j<32;j++) a2[j]=fmaxf((a2[j]-m)*rs*p.g2f[j]+p.be2f[j],0.f);
  }
  float t1=0.f,t2=0.f;
  for(int w=0;w<102;++w){
    float a = p.b3f[w];
    #pragma unroll
    for(int j=0;j<32;j++) a += a2[j]*p.W3f[w*32+j];
    t1+=a; t2+=a*a;
    my[w]=a;
  }
  float mf=t1*(1.f/102.f), rsf=frsq(t2*(1.f/102.f)-mf*mf+1e-5f);
  for(int w=0;w<102;++w) my[w]=sigmf((my[w]-mf)*rsf*p.g3f[w]+p.be3f[w]);
  __syncthreads();
  float* op = p.out + (size_t)blockIdx.x*13056;
  #pragma unroll 1
  for(int m=0;m<26;m++){
    int i4 = tid + 128*m;
    if(i4 < 3264){
      int i0=i4*4;
      float4 v;
      #pragma unroll
      for(int ee=0;ee<4;ee++){
        int idx=i0+ee; int sm=idx/102; int wd=idx-sm*102;
        ((float*)&v)[ee]=sbuf[sm*103+wd];
      }
      *reinterpret_cast<float4*>(op+i0)=v;
    }
  }
}

extern "C" void kernel_launch(void* const* d_in, const int* in_sizes, int n_in,
                              void* d_out, int out_size, void* d_ws, size_t ws_size,
                              hipStream_t stream) {
  (void)in_sizes; (void)n_in; (void)out_size;
  Params p;
  p.x    = (const float*)d_in[0];
  p.Wih0 = (const float*)d_in[1];  p.Whh0 = (const float*)d_in[2];
  p.bih0 = (const float*)d_in[3];  p.bhh0 = (const float*)d_in[4];
  p.Wih1 = (const float*)d_in[5];  p.Whh1 = (const float*)d_in[6];
  p.bih1 = (const float*)d_in[7];  p.bhh1 = (const float*)d_in[8];
  p.fcW  = (const float*)d_in[9];  p.fcb  = (const float*)d_in[10];
  p.W2   = (const float*)d_in[11]; p.b2   = (const float*)d_in[12];
  p.g2   = (const float*)d_in[13]; p.be2  = (const float*)d_in[14];
  p.W3   = (const float*)d_in[15]; p.b3   = (const float*)d_in[16];
  p.g3   = (const float*)d_in[17]; p.be3  = (const float*)d_in[18];
  p.W1f  = (const float*)d_in[19]; p.b1f  = (const float*)d_in[20];
  p.g1f  = (const float*)d_in[21]; p.be1f = (const float*)d_in[22];
  p.W2f  = (const float*)d_in[23]; p.b2f  = (const float*)d_in[24];
  p.g2f  = (const float*)d_in[25]; p.be2f = (const float*)d_in[26];
  p.W3f  = (const float*)d_in[27]; p.b3f  = (const float*)d_in[28];
  p.g3f  = (const float*)d_in[29]; p.be3f = (const float*)d_in[30];
  p.out  = (float*)d_out;

  // ws layout (floats): pv[6*N] | bsum[256] | ptail[1518] | frags (u16)
  const size_t PV_F   = (size_t)6*NSAMP;
  const size_t BS_F   = 256;
  const size_t FRAG_BYTES = (size_t)NFRAG*64*8*2;
  const size_t head_f = PV_F + BS_F + PT_N;
  const size_t need = head_f*4 + FRAG_BYTES;

  if(ws_size >= need){
    float* pv    = (float*)d_ws;
    float* bsum  = pv + PV_F;
    float* ptail = bsum + BS_F;
    unsigned short* frags = (unsigned short*)(ptail + PT_N);
    p.pv = pv; p.ptail = ptail; p.frags = frags;
    prep_kernel<<<1, 256, 0, stream>>>(p, frags, bsum, ptail);
    lstm_kernel<<<NSAMP/64, 256, 0, stream>>>(p.x, frags, bsum, p.fcW, p.fcb, pv);
    tail_kernel<<<NSAMP/64, 256, 0, stream>>>(p);
  } else {
    p.pv = nullptr; p.ptail = nullptr; p.frags = nullptr;
    csnet_mono<<<NSAMP/128, 128, 0, stream>>>(p);
  }
}

// Round 10
// 133.652 us; speedup vs baseline: 3.7806x; 3.7806x over previous
//
#include <hip/hip_runtime.h>

#define DI __device__ __forceinline__
#define NSAMP 65536

typedef __attribute__((ext_vector_type(4))) float f32x4;
typedef __attribute__((ext_vector_type(8))) short short8;
typedef __attribute__((ext_vector_type(4))) short short4v;

DI float frcp(float x){ return __builtin_amdgcn_rcpf(x); }
DI float frsq(float x){ return __builtin_amdgcn_rsqf(x); }
DI float sigmf(float x){ return frcp(1.f + __expf(-x)); }
DI float tanhf_(float x){ return 1.f - 2.f*frcp(__expf(2.f*x) + 1.f); }
DI unsigned short f2bf(float f){                 // RNE float->bf16
  unsigned u = __float_as_uint(f);
  return (unsigned short)((u + 0x7FFFu + ((u>>16)&1u)) >> 16);
}
DI float bf2f(unsigned short h){ return __uint_as_float(((unsigned)h)<<16); }

struct Params {
  const float* __restrict__ x;
  const float* __restrict__ pv;    // [6][NSAMP] (ws)
  const float* __restrict__ ptail; // gathered small params [1518] (ws)
  const unsigned short* __restrict__ frags;
  const float* __restrict__ Wih0; const float* __restrict__ Whh0;
  const float* __restrict__ bih0; const float* __restrict__ bhh0;
  const float* __restrict__ Wih1; const float* __restrict__ Whh1;
  const float* __restrict__ bih1; const float* __restrict__ bhh1;
  const float* __restrict__ fcW;  const float* __restrict__ fcb;
  const float* __restrict__ W2;   const float* __restrict__ b2;
  const float* __restrict__ g2;   const float* __restrict__ be2;
  const float* __restrict__ W3;   const float* __restrict__ b3;
  const float* __restrict__ g3;   const float* __restrict__ be3;
  const float* __restrict__ W1f;  const float* __restrict__ b1f;
  const float* __restrict__ g1f;  const float* __restrict__ be1f;
  const float* __restrict__ W2f;  const float* __restrict__ b2f;
  const float* __restrict__ g2f;  const float* __restrict__ be2f;
  const float* __restrict__ W3f;  const float* __restrict__ b3f;
  const float* __restrict__ g3f;  const float* __restrict__ be3f;
  float* __restrict__ out;
};

// ptail offsets (floats)
#define PT_G2   0
#define PT_BE2  408
#define PT_G3   816
#define PT_BE3  918
#define PT_B1F  1020
#define PT_G1F  1052
#define PT_BE1F 1084
#define PT_B2F  1116
#define PT_G2F  1148
#define PT_BE2F 1180
#define PT_B3F  1212
#define PT_G3F  1314
#define PT_BE3F 1416
#define PT_N    1518
#define NFRAG   49

// ---------- prep: all weight B-fragments (bf16) + bias sums + param gather ----------
__global__ __launch_bounds__(256,1) void prep_kernel(Params p,
    unsigned short* __restrict__ frags, float* __restrict__ bsum,
    float* __restrict__ ptail){
  const int tid = threadIdx.x;
  if(tid < 64){
    const int l15 = tid & 15, g4 = tid >> 4;
    const float* mats[3] = {p.Whh0, p.Wih1, p.Whh1};
    for(int m=0;m<3;m++)
      for(int t=0;t<8;t++){
        const int n = 16*t + l15;
        unsigned short* dst = &frags[((size_t)(m*8+t)*64 + tid)*8];
        for(int j=0;j<4;j++){
          dst[j]   = f2bf(mats[m][n*32 + 4*g4 + j]);
          dst[4+j] = f2bf(mats[m][n*32 + 16 + 4*g4 + j]);
        }
      }
    for(int t=0;t<8;t++){
      const int n = 16*t + l15;
      unsigned short* dst = &frags[((size_t)(24+t)*64 + tid)*8];
      for(int j=0;j<4;j++){
        int k = 4*g4 + j;
        dst[j]   = (k < 3) ? f2bf(p.Wih0[n*3 + k]) : (unsigned short)0;
        dst[4+j] = 0;
      }
    }
    // f1: [108pad128][32] from W1f[32][108] -> idx 32 + kc*2 + nt
    for(int kc=0;kc<4;kc++)
      for(int nt=0;nt<2;nt++){
        const int n = nt*16 + l15;
        unsigned short* dst = &frags[((size_t)(32+kc*2+nt)*64 + tid)*8];
        for(int j=0;j<4;j++){
          int k0 = kc*32 + 4*g4 + j;
          int k1 = kc*32 + 16 + 4*g4 + j;
          dst[j]   = (k0<108) ? f2bf(p.W1f[n*108+k0]) : (unsigned short)0;
          dst[4+j] = (k1<108) ? f2bf(p.W1f[n*108+k1]) : (unsigned short)0;
        }
      }
    // f2: [32][32] -> idx 40+nt
    for(int nt=0;nt<2;nt++){
      const int n = nt*16 + l15;
      unsigned short* dst = &frags[((size_t)(40+nt)*64 + tid)*8];
      for(int j=0;j<4;j++){
        dst[j]   = f2bf(p.W2f[n*32 + 4*g4 + j]);
        dst[4+j] = f2bf(p.W2f[n*32 + 16 + 4*g4 + j]);
      }
    }
    // f3: [32][102pad112] -> idx 42+nt (7 tiles)
    for(int nt=0;nt<7;nt++){
      const int n2 = nt*16 + l15;
      unsigned short* dst = &frags[((size_t)(42+nt)*64 + tid)*8];
      for(int j=0;j<4;j++){
        int k0 = 4*g4 + j, k1 = 16 + 4*g4 + j;
        dst[j]   = (n2<102) ? f2bf(p.W3f[n2*32+k0]) : (unsigned short)0;
        dst[4+j] = (n2<102) ? f2bf(p.W3f[n2*32+k1]) : (unsigned short)0;
      }
    }
  } else if(tid < 192){
    int i = tid - 64;
    bsum[i]       = p.bih0[i] + p.bhh0[i];
    bsum[128 + i] = p.bih1[i] + p.bhh1[i];
  }
  for(int i=tid;i<408;i+=256){ ptail[PT_G2+i]=p.g2[i]; ptail[PT_BE2+i]=p.be2[i]; }
  for(int i=tid;i<102;i+=256){
    ptail[PT_G3+i]=p.g3[i];   ptail[PT_BE3+i]=p.be3[i];
    ptail[PT_B3F+i]=p.b3f[i]; ptail[PT_G3F+i]=p.g3f[i]; ptail[PT_BE3F+i]=p.be3f[i];
  }
  if(tid<32){
    ptail[PT_B1F+tid]=p.b1f[tid];   ptail[PT_G1F+tid]=p.g1f[tid];
    ptail[PT_BE1F+tid]=p.be1f[tid]; ptail[PT_B2F+tid]=p.b2f[tid];
    ptail[PT_G2F+tid]=p.g2f[tid];   ptail[PT_BE2F+tid]=p.be2f[tid];
  }
}

// A-frag from fp32 LDS (lstm h-buffer [16][36])
DI short8 mk_afrag(const float* hbase, int l15, int g4){
  const float4* p0 = (const float4*)(hbase + l15*36 + 4*g4);
  const float4* p1 = (const float4*)(hbase + l15*36 + 16 + 4*g4);
  float4 lo = *p0; float4 hi = *p1;
  short8 s;
  s[0]=(short)f2bf(lo.x); s[1]=(short)f2bf(lo.y); s[2]=(short)f2bf(lo.z); s[3]=(short)f2bf(lo.w);
  s[4]=(short)f2bf(hi.x); s[5]=(short)f2bf(hi.y); s[6]=(short)f2bf(hi.z); s[7]=(short)f2bf(hi.w);
  return s;
}
// A-frag from bf16 LDS, element offset off
DI short8 mk_af16(const unsigned short* lb, int off){
  short4v lo = *(const short4v*)(lb + off);
  short4v hi = *(const short4v*)(lb + off + 16);
  short8 s;
  s[0]=lo[0]; s[1]=lo[1]; s[2]=lo[2]; s[3]=lo[3];
  s[4]=hi[0]; s[5]=hi[1]; s[6]=hi[2]; s[7]=hi[3];
  return s;
}
DI short8 mk_af16_lo(const unsigned short* lb, int off){
  short4v lo = *(const short4v*)(lb + off);
  short8 s;
  s[0]=lo[0]; s[1]=lo[1]; s[2]=lo[2]; s[3]=lo[3];
  s[4]=0; s[5]=0; s[6]=0; s[7]=0;
  return s;
}

// ---------- LSTM via MFMA: 1 wave = 16 samples (unchanged, proven) ----------
__global__ __launch_bounds__(256,1) void lstm_kernel(
    const float* __restrict__ x, const unsigned short* __restrict__ frags,
    const float* __restrict__ bsum, const float* __restrict__ fcW,
    const float* __restrict__ fcb, float* __restrict__ pv){
  __shared__ float hb[4][2][16][36];
  const int tid = threadIdx.x;
  const int w = tid >> 6, l = tid & 63;
  const int l15 = l & 15, g4 = l >> 4;
  const int base = blockIdx.x*64 + w*16;
  const float* __restrict__ xrow = x + (size_t)(base + l15)*348;

  short8 wf[4][8];
  const short8* fsrc = (const short8*)frags;
  #pragma unroll
  for(int m=0;m<4;m++)
    #pragma unroll
    for(int t=0;t<8;t++) wf[m][t] = fsrc[(m*8+t)*64 + l];

  float bfr[2][8];
  #pragma unroll
  for(int t=0;t<8;t++){
    bfr[0][t] = bsum[16*t + l15];
    bfr[1][t] = bsum[128 + 16*t + l15];
  }
  #pragma unroll
  for(int half=0; half<2; half++)
    #pragma unroll
    for(int r=0;r<4;r++){
      hb[w][0][g4*4+r][l15+16*half] = 0.f;
      hb[w][1][g4*4+r][l15+16*half] = 0.f;
    }
  float c0[8], c1[8];
  #pragma unroll
  for(int i=0;i<8;i++){ c0[i]=0.f; c1[i]=0.f; }

  #pragma unroll 1
  for(int t=0;t<4;t++){
    short8 ax;
    {
      float xv0 = xrow[220 + t*3 + 0];
      float xv1 = xrow[220 + t*3 + 1];
      float xv2 = xrow[220 + t*3 + 2];
      bool gz = (g4 == 0);
      ax[0] = gz ? (short)f2bf(xv0) : (short)0;
      ax[1] = gz ? (short)f2bf(xv1) : (short)0;
      ax[2] = gz ? (short)f2bf(xv2) : (short)0;
      ax[3]=0; ax[4]=0; ax[5]=0; ax[6]=0; ax[7]=0;
    }
    short8 ah0 = mk_afrag(&hb[w][0][0][0], l15, g4);
    f32x4 acc0[8];
    #pragma unroll
    for(int n=0;n<8;n++){
      f32x4 a; a[0]=bfr[0][n]; a[1]=bfr[0][n]; a[2]=bfr[0][n]; a[3]=bfr[0][n];
      a = __builtin_amdgcn_mfma_f32_16x16x32_bf16(ax,  wf[3][n], a, 0,0,0);
      a = __builtin_amdgcn_mfma_f32_16x16x32_bf16(ah0, wf[0][n], a, 0,0,0);
      acc0[n] = a;
    }
    #pragma unroll
    for(int half=0; half<2; half++)
      #pragma unroll
      for(int r=0;r<4;r++){
        float gi = acc0[0+half][r], gf = acc0[2+half][r];
        float gg = acc0[4+half][r], go = acc0[6+half][r];
        float cc = sigmf(gf)*c0[half*4+r] + sigmf(gi)*tanhf_(gg);
        c0[half*4+r] = cc;
        hb[w][0][g4*4+r][l15+16*half] = sigmf(go)*tanhf_(cc);
      }
    short8 ah0n = mk_afrag(&hb[w][0][0][0], l15, g4);
    short8 ah1  = mk_afrag(&hb[w][1][0][0], l15, g4);
    f32x4 acc1[8];
    #pragma unroll
    for(int n=0;n<8;n++){
      f32x4 a; a[0]=bfr[1][n]; a[1]=bfr[1][n]; a[2]=bfr[1][n]; a[3]=bfr[1][n];
      a = __builtin_amdgcn_mfma_f32_16x16x32_bf16(ah0n, wf[1][n], a, 0,0,0);
      a = __builtin_amdgcn_mfma_f32_16x16x32_bf16(ah1,  wf[2][n], a, 0,0,0);
      acc1[n] = a;
    }
    #pragma unroll
    for(int half=0; half<2; half++)
      #pragma unroll
      for(int r=0;r<4;r++){
        float gi = acc1[0+half][r], gf = acc1[2+half][r];
        float gg = acc1[4+half][r], go = acc1[6+half][r];
        float cc = sigmf(gf)*c1[half*4+r] + sigmf(gi)*tanhf_(gg);
        c1[half*4+r] = cc;
        hb[w][1][g4*4+r][l15+16*half] = sigmf(go)*tanhf_(cc);
      }
  }
  if(l < 16){
    const int gs = base + l;
    const float* xr2 = x + (size_t)gs*348;
    #pragma unroll
    for(int d=0;d<3;d++){
      float a = fcb[d];
      #pragma unroll
      for(int u=0;u<32;u++) a += hb[w][1][l][u]*fcW[d*32+u];
      float pr = xr2[229 + d];
      pv[(size_t)d*NSAMP + gs]     = a;
      pv[(size_t)(3+d)*NSAMP + gs] = (a - pr)*10.f;
    }
  }
}

DI float rg4(float v){       // reduce across the 4 g4 groups (same l15)
  v += __shfl_xor(v, 16);
  v += __shfl_xor(v, 32);
  return v;
}

// ---------- tail: conv (from LDS-staged bf16 x) + f1/f2/f3 via MFMA ----------
// 1 wave = 16 samples; block = 64 samples. x staged ONCE coalesced (fixes the
// 1.5 GB uncoalesced-read amplification of R9: conv reads were lane=sample,
// rows 1392B apart -> 16 cache lines per load, ~6 rereads per element).
__global__ __launch_bounds__(256,1) void tail_kernel(Params p){
  __shared__ float prm[PT_N];
  __shared__ unsigned int xs32[64*175];    // bf16 x rows [64][348pad350], 44.8 KB
  __shared__ __align__(16) unsigned short lb16[4][16*116];
  const int tid = threadIdx.x;
  const int w = tid >> 6, l = tid & 63;
  const int l15 = l & 15, g4 = l >> 4;
  const int base = blockIdx.x*64 + w*16;
  const int sl   = w*16 + l15;             // block-local sample
  unsigned short* lb = &lb16[w][0];
  const short8* fsrc = (const short8*)p.frags;
  const unsigned short* xsp = (const unsigned short*)xs32;

  for(int i=tid;i<PT_N;i+=256) prm[i]=p.ptail[i];
  // stage 64 x-rows, coalesced float4 -> packed bf16 (row stride 175 u32:
  // 175%32 co-prime with 32 -> 16 consecutive samples hit distinct banks)
  {
    const float4* src = reinterpret_cast<const float4*>(p.x + (size_t)blockIdx.x*64*348);
    #pragma unroll 1
    for(int i=tid; i<64*87; i+=256){
      float4 v = src[i];
      int smp = i/87; int off = i - smp*87;
      unsigned lo = (unsigned)f2bf(v.x) | ((unsigned)f2bf(v.y)<<16);
      unsigned hi = (unsigned)f2bf(v.z) | ((unsigned)f2bf(v.w)<<16);
      xs32[smp*175 + off*2]     = lo;
      xs32[smp*175 + off*2 + 1] = hi;
    }
  }
  // pp/vel into lb slots 102..107, zero 108..115
  if(l < 16){
    #pragma unroll
    for(int d=0;d<3;d++){
      lb[l*116+102+d] = f2bf(p.pv[(size_t)d*NSAMP + base + l]);
      lb[l*116+105+d] = f2bf(p.pv[(size_t)(3+d)*NSAMP + base + l]);
    }
    #pragma unroll
    for(int k=108;k<116;k++) lb[l*116+k] = 0;
  }
  __syncthreads();

  // csi element read: xs[sl][r*116+1+c] as bf16
  #define LDX(r,c) bf2f(xsp[sl*350 + (r)*116 + 1 + (c)])

  const int C0   = g4*26;
  const int ncol = (g4==3) ? 24 : 26;

  // pass 1: LN2 stats
  float s1=0.f, s2=0.f;
  {
    float u0[3],u1[3],u2[3],u3[3],u4[3];
    #pragma unroll
    for(int r=0;r<3;r++){
      u0[r] = (C0-2 >= 0) ? LDX(r, C0-2) : 0.f;
      u1[r] = (C0-1 >= 0) ? LDX(r, C0-1) : 0.f;
      u2[r] = LDX(r, C0);
      u3[r] = LDX(r, C0+1);
      u4[r] = LDX(r, C0+2);
    }
    #pragma unroll 2
    for(int i=0;i<26;i++){
      float msk = (i < ncol) ? 1.f : 0.f;
      #pragma unroll
      for(int o=0;o<4;o++){
        float sv = p.b2[o];
        #pragma unroll
        for(int r=0;r<3;r++)
          sv += u0[r]*p.W2[o*15+r*5+0]+u1[r]*p.W2[o*15+r*5+1]+u2[r]*p.W2[o*15+r*5+2]
              + u3[r]*p.W2[o*15+r*5+3]+u4[r]*p.W2[o*15+r*5+4];
        s1 += msk*sv; s2 += msk*sv*sv;
      }
      int pn = C0 + i + 3;
      int pc = (pn <= 101) ? pn : 101;
      #pragma unroll
      for(int r=0;r<3;r++){
        float nv = LDX(r, pc);
        nv = (pn <= 101) ? nv : 0.f;
        u0[r]=u1[r]; u1[r]=u2[r]; u2[r]=u3[r]; u3[r]=u4[r]; u4[r]=nv;
      }
    }
  }
  float m2  = rg4(s1)*(1.f/408.f);
  float va2 = rg4(s2)*(1.f/408.f) - m2*m2;
  float rs2 = frsq(va2 + 1e-5f);

  // pass 2: recompute + LN2/relu + cv3 -> o3r[26], LN3 stats
  float o3r[26];
  float s31=0.f, s32=0.f;
  {
    float u0[3],u1[3],u2[3],u3[3],u4[3];
    #pragma unroll
    for(int r=0;r<3;r++){
      u0[r] = (C0-2 >= 0) ? LDX(r, C0-2) : 0.f;
      u1[r] = (C0-1 >= 0) ? LDX(r, C0-1) : 0.f;
      u2[r] = LDX(r, C0);
      u3[r] = LDX(r, C0+1);
      u4[r] = LDX(r, C0+2);
    }
    #pragma unroll 2
    for(int i=0;i<26;i++){
      const int wc = (C0+i <= 101) ? C0+i : 101;
      float msk = (i < ncol) ? 1.f : 0.f;
      float o3 = p.b3[0];
      #pragma unroll
      for(int o=0;o<4;o++){
        float sv = p.b2[o];
        #pragma unroll
        for(int r=0;r<3;r++)
          sv += u0[r]*p.W2[o*15+r*5+0]+u1[r]*p.W2[o*15+r*5+1]+u2[r]*p.W2[o*15+r*5+2]
              + u3[r]*p.W2[o*15+r*5+3]+u4[r]*p.W2[o*15+r*5+4];
        float nv = (sv - m2)*rs2*prm[PT_G2+o*102+wc] + prm[PT_BE2+o*102+wc];
        o3 += fmaxf(nv, 0.f)*p.W3[o];
      }
      s31 += msk*o3; s32 += msk*o3*o3;
      o3r[i] = o3;
      int pn = C0 + i + 3;
      int pc = (pn <= 101) ? pn : 101;
      #pragma unroll
      for(int r=0;r<3;r++){
        float nv = LDX(r, pc);
        nv = (pn <= 101) ? nv : 0.f;
        u0[r]=u1[r]; u1[r]=u2[r]; u2[r]=u3[r]; u3[r]=u4[r]; u4[r]=nv;
      }
    }
  }
  #undef LDX
  float m3  = rg4(s31)*(1.f/102.f);
  float va3 = rg4(s32)*(1.f/102.f) - m3*m3;
  float rs3 = frsq(va3 + 1e-5f);

  // LN3 + relu -> lb[sample=l15][col] bf16
  #pragma unroll
  for(int i=0;i<26;i++){
    if(i < ncol){
      const int wc = C0 + i;
      float v = fmaxf((o3r[i]-m3)*rs3*prm[PT_G3+wc] + prm[PT_BE3+wc], 0.f);
      lb[l15*116 + wc] = f2bf(v);
    }
  }

  // ---- f1: [16 x 108pad128] @ [128 x 32] = 8 MFMA ----
  f32x4 a1acc[2];
  {
    float b0v = prm[PT_B1F + l15], b1v = prm[PT_B1F + 16 + l15];
    a1acc[0] = f32x4{b0v,b0v,b0v,b0v};
    a1acc[1] = f32x4{b1v,b1v,b1v,b1v};
  }
  #pragma unroll
  for(int kc=0;kc<4;kc++){
    short8 af = (kc<3) ? mk_af16(lb, l15*116 + kc*32 + 4*g4)
                       : mk_af16_lo(lb, l15*116 + 96 + 4*g4);
    #pragma unroll
    for(int nt=0;nt<2;nt++){
      short8 bf = fsrc[(32+kc*2+nt)*64 + l];
      a1acc[nt] = __builtin_amdgcn_mfma_f32_16x16x32_bf16(af, bf, a1acc[nt], 0,0,0);
    }
  }
  {
    float m1[4], rs1[4];
    #pragma unroll
    for(int r=0;r<4;r++){
      float sm = a1acc[0][r] + a1acc[1][r];
      float sq = a1acc[0][r]*a1acc[0][r] + a1acc[1][r]*a1acc[1][r];
      #pragma unroll
      for(int st=1;st<16;st<<=1){ sm += __shfl_xor(sm,st); sq += __shfl_xor(sq,st); }
      float m = sm*(1.f/32.f);
      m1[r]=m; rs1[r]=frsq(sq*(1.f/32.f)-m*m+1e-5f);
    }
    #pragma unroll
    for(int nt=0;nt<2;nt++){
      float g  = prm[PT_G1F + nt*16 + l15];
      float be = prm[PT_BE1F + nt*16 + l15];
      #pragma unroll
      for(int r=0;r<4;r++){
        float vv = fmaxf((a1acc[nt][r]-m1[r])*rs1[r]*g + be, 0.f);
        lb[(4*g4+r)*116 + nt*16 + l15] = f2bf(vv);
      }
    }
  }

  // ---- f2: [16 x 32] @ [32 x 32] = 2 MFMA ----
  {
    f32x4 a2acc[2];
    float b0v = prm[PT_B2F + l15], b1v = prm[PT_B2F + 16 + l15];
    a2acc[0] = f32x4{b0v,b0v,b0v,b0v};
    a2acc[1] = f32x4{b1v,b1v,b1v,b1v};
    short8 af = mk_af16(lb, l15*116 + 4*g4);
    #pragma unroll
    for(int nt=0;nt<2;nt++){
      short8 bf = fsrc[(40+nt)*64 + l];
      a2acc[nt] = __builtin_amdgcn_mfma_f32_16x16x32_bf16(af, bf, a2acc[nt], 0,0,0);
    }
    float m1[4], rs1[4];
    #pragma unroll
    for(int r=0;r<4;r++){
      float sm = a2acc[0][r] + a2acc[1][r];
      float sq = a2acc[0][r]*a2acc[0][r] + a2acc[1][r]*a2acc[1][r];
      #pragma unroll
      for(int st=1;st<16;st<<=1){ sm += __shfl_xor(sm,st); sq += __shfl_xor(sq,st); }
      float m = sm*(1.f/32.f);
      m1[r]=m; rs1[r]=frsq(sq*(1.f/32.f)-m*m+1e-5f);
    }
    #pragma unroll
    for(int nt=0;nt<2;nt++){
      float g  = prm[PT_G2F + nt*16 + l15];
      float be = prm[PT_BE2F + nt*16 + l15];
      #pragma unroll
      for(int r=0;r<4;r++){
        float vv = fmaxf((a2acc[nt][r]-m1[r])*rs1[r]*g + be, 0.f);
        lb[(4*g4+r)*116 + nt*16 + l15] = f2bf(vv);
      }
    }
  }

  // ---- f3: [16 x 32] @ [32 x 102pad112] = 7 MFMA ----
  {
    f32x4 a3[7];
    float mskt[7];
    #pragma unroll
    for(int nt=0;nt<7;nt++){
      int n2 = nt*16 + l15;
      mskt[nt] = (n2 < 102) ? 1.f : 0.f;
      float bv = prm[PT_B3F + ((n2<102)?n2:0)] * mskt[nt];
      a3[nt] = f32x4{bv,bv,bv,bv};
    }
    short8 af = mk_af16(lb, l15*116 + 4*g4);
    #pragma unroll
    for(int nt=0;nt<7;nt++){
      short8 bf = fsrc[(42+nt)*64 + l];
      a3[nt] = __builtin_amdgcn_mfma_f32_16x16x32_bf16(af, bf, a3[nt], 0,0,0);
    }
    float mf[4], rsf[4];
    #pragma unroll
    for(int r=0;r<4;r++){
      float sm=0.f, sq=0.f;
      #pragma unroll
      for(int nt=0;nt<7;nt++){
        float vv = a3[nt][r];
        sm += mskt[nt]*vv; sq += mskt[nt]*vv*vv;
      }
      #pragma unroll
      for(int st=1;st<16;st<<=1){ sm += __shfl_xor(sm,st); sq += __shfl_xor(sq,st); }
      float m = sm*(1.f/102.f);
      mf[r]=m; rsf[r]=frsq(sq*(1.f/102.f)-m*m+1e-5f);
    }
    #pragma unroll
    for(int nt=0;nt<7;nt++){
      int n2 = nt*16 + l15;
      if(n2 < 102){
        float g  = prm[PT_G3F + n2];
        float be = prm[PT_BE3F + n2];
        #pragma unroll
        for(int r=0;r<4;r++){
          float val = sigmf((a3[nt][r]-mf[r])*rsf[r]*g + be);
          p.out[(size_t)(base + 4*g4 + r)*102 + n2] = val;
        }
      }
    }
  }
}

// ---------- AoS monolithic fallback (R1, proven) ----------
template<int IN>
DI void lstm_step(const float* __restrict__ Wih, const float* __restrict__ Whh,
                  const float* __restrict__ bih, const float* __restrict__ bhh,
                  const float* xin, const float* hin, float* c, float* hout){
  #pragma unroll
  for(int j=0;j<32;j++){
    float ai = bih[j]    + bhh[j];
    float af = bih[32+j] + bhh[32+j];
    float ag = bih[64+j] + bhh[64+j];
    float ao = bih[96+j] + bhh[96+j];
    #pragma unroll
    for(int k=0;k<IN;k++){
      float xv = xin[k];
      ai += xv*Wih[j*IN+k]; af += xv*Wih[(32+j)*IN+k];
      ag += xv*Wih[(64+j)*IN+k]; ao += xv*Wih[(96+j)*IN+k];
    }
    #pragma unroll
    for(int k=0;k<32;k++){
      float hv = hin[k];
      ai += hv*Whh[j*32+k]; af += hv*Whh[(32+j)*32+k];
      ag += hv*Whh[(64+j)*32+k]; ao += hv*Whh[(96+j)*32+k];
    }
    float cc = sigmf(af)*c[j] + sigmf(ai)*tanhf_(ag);
    c[j] = cc;
    hout[j] = sigmf(ao)*tanhf_(cc);
  }
}

__global__ __launch_bounds__(128,1) void csnet_mono(Params p){
  const int tid = threadIdx.x;
  const int b = blockIdx.x*128 + tid;
  const float* __restrict__ xr = p.x + (size_t)b*348;
  __shared__ float sbuf[128*103];
  float* my = &sbuf[tid*103];
  float h0[32], c0[32], h1[32], c1[32];
  #pragma unroll
  for(int j=0;j<32;j++){ h0[j]=0.f; c0[j]=0.f; h1[j]=0.f; c1[j]=0.f; }
  #pragma unroll 1
  for(int t=0;t<4;t++){
    float xt[3];
    #pragma unroll
    for(int d=0;d<3;d++) xt[d] = xr[220 + t*3 + d];
    float hA[32], hB[32];
    lstm_step<3 >(p.Wih0,p.Whh0,p.bih0,p.bhh0, xt, h0, c0, hA);
    lstm_step<32>(p.Wih1,p.Whh1,p.bih1,p.bhh1, hA, h1, c1, hB);
    #pragma unroll
    for(int j=0;j<32;j++){ h0[j]=hA[j]; h1[j]=hB[j]; }
  }
  float pp[3], vel[3];
  #pragma unroll
  for(int d=0;d<3;d++){
    float a = p.fcb[d];
    #pragma unroll
    for(int j=0;j<32;j++) a += h1[j]*p.fcW[d*32+j];
    pp[d]  = a;
    vel[d] = (a - xr[229+d])*10.f;
  }
  float s1 = 0.f, s2 = 0.f;
  for(int w=0; w<102; ++w){
    #pragma unroll
    for(int o=0;o<4;o++){
      float s = p.b2[o];
      #pragma unroll
      for(int r=0;r<3;r++)
        #pragma unroll
        for(int kk=0;kk<5;kk++){
          int c = w - 2 + kk;
          float v = (c>=0 && c<=101) ? xr[r*116 + 1 + (c<0?0:(c>101?101:c))] : 0.f;
          s += v*p.W2[o*15 + r*5 + kk];
        }
      s1 += s; s2 += s*s;
    }
  }
  float m2  = s1*(1.f/408.f);
  float rs2 = frsq(s2*(1.f/408.f) - m2*m2 + 1e-5f);
  float s31=0.f, s32=0.f;
  for(int w=0; w<102; ++w){
    float o3 = p.b3[0];
    #pragma unroll
    for(int o=0;o<4;o++){
      float s = p.b2[o];
      #pragma unroll
      for(int r=0;r<3;r++)
        #pragma unroll
        for(int kk=0;kk<5;kk++){
          int c = w - 2 + kk;
          float v = (c>=0 && c<=101) ? xr[r*116 + 1 + (c<0?0:(c>101?101:c))] : 0.f;
          s += v*p.W2[o*15 + r*5 + kk];
        }
      float nv = (s - m2)*rs2*p.g2[o*102+w] + p.be2[o*102+w];
      o3 += fmaxf(nv, 0.f)*p.W3[o];
    }
    s31 += o3; s32 += o3*o3;
    my[w] = o3;
  }
  float m3  = s31*(1.f/102.f);
  float rs3 = frsq(s32*(1.f/102.f) - m3*m3 + 1e-5f);
  float a1[32];
  #pragma unroll
  for(int j=0;j<32;j++) a1[j] = p.b1f[j];
  for(int w=0; w<102; ++w){
    float v = fmaxf((my[w]-m3)*rs3*p.g3[w] + p.be3[w], 0.f);
    #pragma unroll
    for(int j=0;j<32;j++) a1[j] += v*p.W1f[j*108+w];
  }
  #pragma unroll
  for(int d=0;d<3;d++)
    #pragma unroll
    for(int j=0;j<32;j++){
      a1[j] += pp[d]*p.W1f[j*108+102+d];
      a1[j] += vel[d]*p.W1f[j*108+105+d];
    }
  {
    float s=0.f,qq=0.f;
    #pragma unroll
    for(int j=0;j<32;j++){ s+=a1[j]; qq+=a1[j]*a1[j]; }
    float m=s*(1.f/32.f), rs=frsq(qq*(1.f/32.f)-m*m+1e-5f);
    #pragma unroll
    for(int j=0;j<32;j++) a1[j]=fmaxf((a1[j]-m)*rs*p.g1f[j]+p.be1f[j],0.f);
  }
  float a2[32];
  #pragma unroll
  for(int j=0;j<32;j++){
    float a = p.b2f[j];
    #pragma unroll
    for(int k=0;k<32;k++) a += a1[k]*p.W2f[j*32+k];
    a2[j]=a;
  }
  {
    float s=0.f,qq=0.f;
    #pragma unroll
    for(int j=0;j<32;j++){ s+=a2[j]; qq+=a2[j]*a2[j]; }
    float m=s*(1.f/32.f), rs=frsq(qq*(1.f/32.f)-m*m+1e-5f);
    #pragma unroll
    for(int j=0;j<32;j++) a2[j]=fmaxf((a2[j]-m)*rs*p.g2f[j]+p.be2f[j],0.f);
  }
  float t1=0.f,t2=0.f;
  for(int w=0;w<102;++w){
    float a = p.b3f[w];
    #pragma unroll
    for(int j=0;j<32;j++) a += a2[j]*p.W3f[w*32+j];
    t1+=a; t2+=a*a;
    my[w]=a;
  }
  float mf=t1*(1.f/102.f), rsf=frsq(t2*(1.f/102.f)-mf*mf+1e-5f);
  for(int w=0;w<102;++w) my[w]=sigmf((my[w]-mf)*rsf*p.g3f[w]+p.be3f[w]);
  __syncthreads();
  float* op = p.out + (size_t)blockIdx.x*13056;
  #pragma unroll 1
  for(int m=0;m<26;m++){
    int i4 = tid + 128*m;
    if(i4 < 3264){
      int i0=i4*4;
      float4 v;
      #pragma unroll
      for(int ee=0;ee<4;ee++){
        int idx=i0+ee; int sm=idx/102; int wd=idx-sm*102;
        ((float*)&v)[ee]=sbuf[sm*103+wd];
      }
      *reinterpret_cast<float4*>(op+i0)=v;
    }
  }
}

extern "C" void kernel_launch(void* const* d_in, const int* in_sizes, int n_in,
                              void* d_out, int out_size, void* d_ws, size_t ws_size,
                              hipStream_t stream) {
  (void)in_sizes; (void)n_in; (void)out_size;
  Params p;
  p.x    = (const float*)d_in[0];
  p.Wih0 = (const float*)d_in[1];  p.Whh0 = (const float*)d_in[2];
  p.bih0 = (const float*)d_in[3];  p.bhh0 = (const float*)d_in[4];
  p.Wih1 = (const float*)d_in[5];  p.Whh1 = (const float*)d_in[6];
  p.bih1 = (const float*)d_in[7];  p.bhh1 = (const float*)d_in[8];
  p.fcW  = (const float*)d_in[9];  p.fcb  = (const float*)d_in[10];
  p.W2   = (const float*)d_in[11]; p.b2   = (const float*)d_in[12];
  p.g2   = (const float*)d_in[13]; p.be2  = (const float*)d_in[14];
  p.W3   = (const float*)d_in[15]; p.b3   = (const float*)d_in[16];
  p.g3   = (const float*)d_in[17]; p.be3  = (const float*)d_in[18];
  p.W1f  = (const float*)d_in[19]; p.b1f  = (const float*)d_in[20];
  p.g1f  = (const float*)d_in[21]; p.be1f = (const float*)d_in[22];
  p.W2f  = (const float*)d_in[23]; p.b2f  = (const float*)d_in[24];
  p.g2f  = (const float*)d_in[25]; p.be2f = (const float*)d_in[26];
  p.W3f  = (const float*)d_in[27]; p.b3f  = (const float*)d_in[28];
  p.g3f  = (const float*)d_in[29]; p.be3f = (const float*)d_in[30];
  p.out  = (float*)d_out;

  // ws layout (floats): pv[6*N] | bsum[256] | ptail[1518] | frags (u16)
  const size_t PV_F   = (size_t)6*NSAMP;
  const size_t BS_F   = 256;
  const size_t FRAG_BYTES = (size_t)NFRAG*64*8*2;
  const size_t head_f = PV_F + BS_F + PT_N;
  const size_t need = head_f*4 + FRAG_BYTES;

  if(ws_size >= need){
    float* pv    = (float*)d_ws;
    float* bsum  = pv + PV_F;
    float* ptail = bsum + BS_F;
    unsigned short* frags = (unsigned short*)(ptail + PT_N);
    p.pv = pv; p.ptail = ptail; p.frags = frags;
    prep_kernel<<<1, 256, 0, stream>>>(p, frags, bsum, ptail);
    lstm_kernel<<<NSAMP/64, 256, 0, stream>>>(p.x, frags, bsum, p.fcW, p.fcb, pv);
    tail_kernel<<<NSAMP/64, 256, 0, stream>>>(p);
  } else {
    p.pv = nullptr; p.ptail = nullptr; p.frags = nullptr;
    csnet_mono<<<NSAMP/128, 128, 0, stream>>>(p);
  }
}

// Round 11
// 127.770 us; speedup vs baseline: 3.9547x; 1.0460x over previous
//
#include <hip/hip_runtime.h>

#define DI __device__ __forceinline__
#define NSAMP 65536

typedef __attribute__((ext_vector_type(4))) float f32x4;
typedef __attribute__((ext_vector_type(8))) short short8;
typedef __attribute__((ext_vector_type(4))) short short4v;

DI float frcp(float x){ return __builtin_amdgcn_rcpf(x); }
DI float frsq(float x){ return __builtin_amdgcn_rsqf(x); }
DI float sigmf(float x){ return frcp(1.f + __expf(-x)); }
DI float tanhf_(float x){ return 1.f - 2.f*frcp(__expf(2.f*x) + 1.f); }
DI unsigned short f2bf(float f){                 // RNE float->bf16
  unsigned u = __float_as_uint(f);
  return (unsigned short)((u + 0x7FFFu + ((u>>16)&1u)) >> 16);
}
DI float bf2f(unsigned short h){ return __uint_as_float(((unsigned)h)<<16); }

struct Params {
  const float* __restrict__ x;
  const float* __restrict__ pv;    // [6][NSAMP] (ws)
  const float* __restrict__ ptail; // gathered small params [1518] (ws)
  const unsigned short* __restrict__ frags;
  const float* __restrict__ Wih0; const float* __restrict__ Whh0;
  const float* __restrict__ bih0; const float* __restrict__ bhh0;
  const float* __restrict__ Wih1; const float* __restrict__ Whh1;
  const float* __restrict__ bih1; const float* __restrict__ bhh1;
  const float* __restrict__ fcW;  const float* __restrict__ fcb;
  const float* __restrict__ W2;   const float* __restrict__ b2;
  const float* __restrict__ g2;   const float* __restrict__ be2;
  const float* __restrict__ W3;   const float* __restrict__ b3;
  const float* __restrict__ g3;   const float* __restrict__ be3;
  const float* __restrict__ W1f;  const float* __restrict__ b1f;
  const float* __restrict__ g1f;  const float* __restrict__ be1f;
  const float* __restrict__ W2f;  const float* __restrict__ b2f;
  const float* __restrict__ g2f;  const float* __restrict__ be2f;
  const float* __restrict__ W3f;  const float* __restrict__ b3f;
  const float* __restrict__ g3f;  const float* __restrict__ be3f;
  float* __restrict__ out;
};

// ptail offsets (floats)
#define PT_G2   0
#define PT_BE2  408
#define PT_G3   816
#define PT_BE3  918
#define PT_B1F  1020
#define PT_G1F  1052
#define PT_BE1F 1084
#define PT_B2F  1116
#define PT_G2F  1148
#define PT_BE2F 1180
#define PT_B3F  1212
#define PT_G3F  1314
#define PT_BE3F 1416
#define PT_N    1518
#define NFRAG   49

// ---------- prep: all weight B-fragments (bf16) + bias sums + param gather ----------
__global__ __launch_bounds__(256,1) void prep_kernel(Params p,
    unsigned short* __restrict__ frags, float* __restrict__ bsum,
    float* __restrict__ ptail){
  const int tid = threadIdx.x;
  if(tid < 64){
    const int l15 = tid & 15, g4 = tid >> 4;
    const float* mats[3] = {p.Whh0, p.Wih1, p.Whh1};
    for(int m=0;m<3;m++)
      for(int t=0;t<8;t++){
        const int n = 16*t + l15;
        unsigned short* dst = &frags[((size_t)(m*8+t)*64 + tid)*8];
        for(int j=0;j<4;j++){
          dst[j]   = f2bf(mats[m][n*32 + 4*g4 + j]);
          dst[4+j] = f2bf(mats[m][n*32 + 16 + 4*g4 + j]);
        }
      }
    for(int t=0;t<8;t++){
      const int n = 16*t + l15;
      unsigned short* dst = &frags[((size_t)(24+t)*64 + tid)*8];
      for(int j=0;j<4;j++){
        int k = 4*g4 + j;
        dst[j]   = (k < 3) ? f2bf(p.Wih0[n*3 + k]) : (unsigned short)0;
        dst[4+j] = 0;
      }
    }
    // f1: [108pad128][32] from W1f[32][108] -> idx 32 + kc*2 + nt
    for(int kc=0;kc<4;kc++)
      for(int nt=0;nt<2;nt++){
        const int n = nt*16 + l15;
        unsigned short* dst = &frags[((size_t)(32+kc*2+nt)*64 + tid)*8];
        for(int j=0;j<4;j++){
          int k0 = kc*32 + 4*g4 + j;
          int k1 = kc*32 + 16 + 4*g4 + j;
          dst[j]   = (k0<108) ? f2bf(p.W1f[n*108+k0]) : (unsigned short)0;
          dst[4+j] = (k1<108) ? f2bf(p.W1f[n*108+k1]) : (unsigned short)0;
        }
      }
    // f2: [32][32] -> idx 40+nt
    for(int nt=0;nt<2;nt++){
      const int n = nt*16 + l15;
      unsigned short* dst = &frags[((size_t)(40+nt)*64 + tid)*8];
      for(int j=0;j<4;j++){
        dst[j]   = f2bf(p.W2f[n*32 + 4*g4 + j]);
        dst[4+j] = f2bf(p.W2f[n*32 + 16 + 4*g4 + j]);
      }
    }
    // f3: [32][102pad112] -> idx 42+nt (7 tiles)
    for(int nt=0;nt<7;nt++){
      const int n2 = nt*16 + l15;
      unsigned short* dst = &frags[((size_t)(42+nt)*64 + tid)*8];
      for(int j=0;j<4;j++){
        int k0 = 4*g4 + j, k1 = 16 + 4*g4 + j;
        dst[j]   = (n2<102) ? f2bf(p.W3f[n2*32+k0]) : (unsigned short)0;
        dst[4+j] = (n2<102) ? f2bf(p.W3f[n2*32+k1]) : (unsigned short)0;
      }
    }
  } else if(tid < 192){
    int i = tid - 64;
    bsum[i]       = p.bih0[i] + p.bhh0[i];
    bsum[128 + i] = p.bih1[i] + p.bhh1[i];
  }
  for(int i=tid;i<408;i+=256){ ptail[PT_G2+i]=p.g2[i]; ptail[PT_BE2+i]=p.be2[i]; }
  for(int i=tid;i<102;i+=256){
    ptail[PT_G3+i]=p.g3[i];   ptail[PT_BE3+i]=p.be3[i];
    ptail[PT_B3F+i]=p.b3f[i]; ptail[PT_G3F+i]=p.g3f[i]; ptail[PT_BE3F+i]=p.be3f[i];
  }
  if(tid<32){
    ptail[PT_B1F+tid]=p.b1f[tid];   ptail[PT_G1F+tid]=p.g1f[tid];
    ptail[PT_BE1F+tid]=p.be1f[tid]; ptail[PT_B2F+tid]=p.b2f[tid];
    ptail[PT_G2F+tid]=p.g2f[tid];   ptail[PT_BE2F+tid]=p.be2f[tid];
  }
}

// A-frag from fp32 LDS (lstm h-buffer [16][36])
DI short8 mk_afrag(const float* hbase, int l15, int g4){
  const float4* p0 = (const float4*)(hbase + l15*36 + 4*g4);
  const float4* p1 = (const float4*)(hbase + l15*36 + 16 + 4*g4);
  float4 lo = *p0; float4 hi = *p1;
  short8 s;
  s[0]=(short)f2bf(lo.x); s[1]=(short)f2bf(lo.y); s[2]=(short)f2bf(lo.z); s[3]=(short)f2bf(lo.w);
  s[4]=(short)f2bf(hi.x); s[5]=(short)f2bf(hi.y); s[6]=(short)f2bf(hi.z); s[7]=(short)f2bf(hi.w);
  return s;
}
// A-frag from bf16 LDS, element offset off
DI short8 mk_af16(const unsigned short* lb, int off){
  short4v lo = *(const short4v*)(lb + off);
  short4v hi = *(const short4v*)(lb + off + 16);
  short8 s;
  s[0]=lo[0]; s[1]=lo[1]; s[2]=lo[2]; s[3]=lo[3];
  s[4]=hi[0]; s[5]=hi[1]; s[6]=hi[2]; s[7]=hi[3];
  return s;
}
DI short8 mk_af16_lo(const unsigned short* lb, int off){
  short4v lo = *(const short4v*)(lb + off);
  short8 s;
  s[0]=lo[0]; s[1]=lo[1]; s[2]=lo[2]; s[3]=lo[3];
  s[4]=0; s[5]=0; s[6]=0; s[7]=0;
  return s;
}

// ---------- LSTM via MFMA: 1 wave = 16 samples (unchanged, proven) ----------
__global__ __launch_bounds__(256,1) void lstm_kernel(
    const float* __restrict__ x, const unsigned short* __restrict__ frags,
    const float* __restrict__ bsum, const float* __restrict__ fcW,
    const float* __restrict__ fcb, float* __restrict__ pv){
  __shared__ float hb[4][2][16][36];
  const int tid = threadIdx.x;
  const int w = tid >> 6, l = tid & 63;
  const int l15 = l & 15, g4 = l >> 4;
  const int base = blockIdx.x*64 + w*16;
  const float* __restrict__ xrow = x + (size_t)(base + l15)*348;

  short8 wf[4][8];
  const short8* fsrc = (const short8*)frags;
  #pragma unroll
  for(int m=0;m<4;m++)
    #pragma unroll
    for(int t=0;t<8;t++) wf[m][t] = fsrc[(m*8+t)*64 + l];

  float bfr[2][8];
  #pragma unroll
  for(int t=0;t<8;t++){
    bfr[0][t] = bsum[16*t + l15];
    bfr[1][t] = bsum[128 + 16*t + l15];
  }
  #pragma unroll
  for(int half=0; half<2; half++)
    #pragma unroll
    for(int r=0;r<4;r++){
      hb[w][0][g4*4+r][l15+16*half] = 0.f;
      hb[w][1][g4*4+r][l15+16*half] = 0.f;
    }
  float c0[8], c1[8];
  #pragma unroll
  for(int i=0;i<8;i++){ c0[i]=0.f; c1[i]=0.f; }

  #pragma unroll 1
  for(int t=0;t<4;t++){
    short8 ax;
    {
      float xv0 = xrow[220 + t*3 + 0];
      float xv1 = xrow[220 + t*3 + 1];
      float xv2 = xrow[220 + t*3 + 2];
      bool gz = (g4 == 0);
      ax[0] = gz ? (short)f2bf(xv0) : (short)0;
      ax[1] = gz ? (short)f2bf(xv1) : (short)0;
      ax[2] = gz ? (short)f2bf(xv2) : (short)0;
      ax[3]=0; ax[4]=0; ax[5]=0; ax[6]=0; ax[7]=0;
    }
    short8 ah0 = mk_afrag(&hb[w][0][0][0], l15, g4);
    f32x4 acc0[8];
    #pragma unroll
    for(int n=0;n<8;n++){
      f32x4 a; a[0]=bfr[0][n]; a[1]=bfr[0][n]; a[2]=bfr[0][n]; a[3]=bfr[0][n];
      a = __builtin_amdgcn_mfma_f32_16x16x32_bf16(ax,  wf[3][n], a, 0,0,0);
      a = __builtin_amdgcn_mfma_f32_16x16x32_bf16(ah0, wf[0][n], a, 0,0,0);
      acc0[n] = a;
    }
    #pragma unroll
    for(int half=0; half<2; half++)
      #pragma unroll
      for(int r=0;r<4;r++){
        float gi = acc0[0+half][r], gf = acc0[2+half][r];
        float gg = acc0[4+half][r], go = acc0[6+half][r];
        float cc = sigmf(gf)*c0[half*4+r] + sigmf(gi)*tanhf_(gg);
        c0[half*4+r] = cc;
        hb[w][0][g4*4+r][l15+16*half] = sigmf(go)*tanhf_(cc);
      }
    short8 ah0n = mk_afrag(&hb[w][0][0][0], l15, g4);
    short8 ah1  = mk_afrag(&hb[w][1][0][0], l15, g4);
    f32x4 acc1[8];
    #pragma unroll
    for(int n=0;n<8;n++){
      f32x4 a; a[0]=bfr[1][n]; a[1]=bfr[1][n]; a[2]=bfr[1][n]; a[3]=bfr[1][n];
      a = __builtin_amdgcn_mfma_f32_16x16x32_bf16(ah0n, wf[1][n], a, 0,0,0);
      a = __builtin_amdgcn_mfma_f32_16x16x32_bf16(ah1,  wf[2][n], a, 0,0,0);
      acc1[n] = a;
    }
    #pragma unroll
    for(int half=0; half<2; half++)
      #pragma unroll
      for(int r=0;r<4;r++){
        float gi = acc1[0+half][r], gf = acc1[2+half][r];
        float gg = acc1[4+half][r], go = acc1[6+half][r];
        float cc = sigmf(gf)*c1[half*4+r] + sigmf(gi)*tanhf_(gg);
        c1[half*4+r] = cc;
        hb[w][1][g4*4+r][l15+16*half] = sigmf(go)*tanhf_(cc);
      }
  }
  if(l < 16){
    const int gs = base + l;
    const float* xr2 = x + (size_t)gs*348;
    #pragma unroll
    for(int d=0;d<3;d++){
      float a = fcb[d];
      #pragma unroll
      for(int u=0;u<32;u++) a += hb[w][1][l][u]*fcW[d*32+u];
      float pr = xr2[229 + d];
      pv[(size_t)d*NSAMP + gs]     = a;
      pv[(size_t)(3+d)*NSAMP + gs] = (a - pr)*10.f;
    }
  }
}

DI float rg4(float v){       // reduce across the 4 g4 groups (same l15)
  v += __shfl_xor(v, 16);
  v += __shfl_xor(v, 32);
  return v;
}

// ---------- tail: conv (from LDS-staged bf16 x) + f1/f2/f3 via MFMA ----------
// LDS trimmed to ~51 KB for 3 blocks/CU: the activation buffer lb OVERLAYS the
// wave's own 16 xs-rows (wave-private; xs dead once this wave's conv finishes;
// pp/vel writes moved to after the conv so no early writes touch the overlay).
__global__ __launch_bounds__(256,1) void tail_kernel(Params p){
  __shared__ float prm[PT_N];
  __shared__ unsigned int xs32[64*175];    // bf16 x rows [64][348pad350], 44.8 KB
  const int tid = threadIdx.x;
  const int w = tid >> 6, l = tid & 63;
  const int l15 = l & 15, g4 = l >> 4;
  const int base = blockIdx.x*64 + w*16;
  const int sl   = w*16 + l15;             // block-local sample
  // lb overlays this wave's xs region (928 u32 needed of 2800; 16B-aligned)
  unsigned short* lb = (unsigned short*)(xs32 + w*16*175);
  const short8* fsrc = (const short8*)p.frags;
  const unsigned short* xsp = (const unsigned short*)xs32;

  for(int i=tid;i<PT_N;i+=256) prm[i]=p.ptail[i];
  // stage 64 x-rows, coalesced float4 -> packed bf16 (row stride 175 u32)
  {
    const float4* src = reinterpret_cast<const float4*>(p.x + (size_t)blockIdx.x*64*348);
    #pragma unroll 1
    for(int i=tid; i<64*87; i+=256){
      float4 v = src[i];
      int smp = i/87; int off = i - smp*87;
      unsigned lo = (unsigned)f2bf(v.x) | ((unsigned)f2bf(v.y)<<16);
      unsigned hi = (unsigned)f2bf(v.z) | ((unsigned)f2bf(v.w)<<16);
      xs32[smp*175 + off*2]     = lo;
      xs32[smp*175 + off*2 + 1] = hi;
    }
  }
  __syncthreads();

  // csi element read: xs[sl][r*116+1+c] as bf16
  #define LDX(r,c) bf2f(xsp[sl*350 + (r)*116 + 1 + (c)])

  const int C0   = g4*26;
  const int ncol = (g4==3) ? 24 : 26;

  // pass 1: LN2 stats
  float s1=0.f, s2=0.f;
  {
    float u0[3],u1[3],u2[3],u3[3],u4[3];
    #pragma unroll
    for(int r=0;r<3;r++){
      u0[r] = (C0-2 >= 0) ? LDX(r, C0-2) : 0.f;
      u1[r] = (C0-1 >= 0) ? LDX(r, C0-1) : 0.f;
      u2[r] = LDX(r, C0);
      u3[r] = LDX(r, C0+1);
      u4[r] = LDX(r, C0+2);
    }
    #pragma unroll 2
    for(int i=0;i<26;i++){
      float msk = (i < ncol) ? 1.f : 0.f;
      #pragma unroll
      for(int o=0;o<4;o++){
        float sv = p.b2[o];
        #pragma unroll
        for(int r=0;r<3;r++)
          sv += u0[r]*p.W2[o*15+r*5+0]+u1[r]*p.W2[o*15+r*5+1]+u2[r]*p.W2[o*15+r*5+2]
              + u3[r]*p.W2[o*15+r*5+3]+u4[r]*p.W2[o*15+r*5+4];
        s1 += msk*sv; s2 += msk*sv*sv;
      }
      int pn = C0 + i + 3;
      int pc = (pn <= 101) ? pn : 101;
      #pragma unroll
      for(int r=0;r<3;r++){
        float nv = LDX(r, pc);
        nv = (pn <= 101) ? nv : 0.f;
        u0[r]=u1[r]; u1[r]=u2[r]; u2[r]=u3[r]; u3[r]=u4[r]; u4[r]=nv;
      }
    }
  }
  float m2  = rg4(s1)*(1.f/408.f);
  float va2 = rg4(s2)*(1.f/408.f) - m2*m2;
  float rs2 = frsq(va2 + 1e-5f);

  // pass 2: recompute + LN2/relu + cv3 -> o3r[26], LN3 stats
  float o3r[26];
  float s31=0.f, s32=0.f;
  {
    float u0[3],u1[3],u2[3],u3[3],u4[3];
    #pragma unroll
    for(int r=0;r<3;r++){
      u0[r] = (C0-2 >= 0) ? LDX(r, C0-2) : 0.f;
      u1[r] = (C0-1 >= 0) ? LDX(r, C0-1) : 0.f;
      u2[r] = LDX(r, C0);
      u3[r] = LDX(r, C0+1);
      u4[r] = LDX(r, C0+2);
    }
    #pragma unroll 2
    for(int i=0;i<26;i++){
      const int wc = (C0+i <= 101) ? C0+i : 101;
      float msk = (i < ncol) ? 1.f : 0.f;
      float o3 = p.b3[0];
      #pragma unroll
      for(int o=0;o<4;o++){
        float sv = p.b2[o];
        #pragma unroll
        for(int r=0;r<3;r++)
          sv += u0[r]*p.W2[o*15+r*5+0]+u1[r]*p.W2[o*15+r*5+1]+u2[r]*p.W2[o*15+r*5+2]
              + u3[r]*p.W2[o*15+r*5+3]+u4[r]*p.W2[o*15+r*5+4];
        float nv = (sv - m2)*rs2*prm[PT_G2+o*102+wc] + prm[PT_BE2+o*102+wc];
        o3 += fmaxf(nv, 0.f)*p.W3[o];
      }
      s31 += msk*o3; s32 += msk*o3*o3;
      o3r[i] = o3;
      int pn = C0 + i + 3;
      int pc = (pn <= 101) ? pn : 101;
      #pragma unroll
      for(int r=0;r<3;r++){
        float nv = LDX(r, pc);
        nv = (pn <= 101) ? nv : 0.f;
        u0[r]=u1[r]; u1[r]=u2[r]; u2[r]=u3[r]; u3[r]=u4[r]; u4[r]=nv;
      }
    }
  }
  #undef LDX
  float m3  = rg4(s31)*(1.f/102.f);
  float va3 = rg4(s32)*(1.f/102.f) - m3*m3;
  float rs3 = frsq(va3 + 1e-5f);

  // xs region for THIS WAVE is now dead -> safe to write lb overlay.
  // LN3 + relu -> lb[sample=l15][col] bf16
  #pragma unroll
  for(int i=0;i<26;i++){
    if(i < ncol){
      const int wc = C0 + i;
      float v = fmaxf((o3r[i]-m3)*rs3*prm[PT_G3+wc] + prm[PT_BE3+wc], 0.f);
      lb[l15*116 + wc] = f2bf(v);
    }
  }
  // pp/vel into lb slots 102..107, zero 108..115 (moved here from pre-sync)
  if(l < 16){
    #pragma unroll
    for(int d=0;d<3;d++){
      lb[l*116+102+d] = f2bf(p.pv[(size_t)d*NSAMP + base + l]);
      lb[l*116+105+d] = f2bf(p.pv[(size_t)(3+d)*NSAMP + base + l]);
    }
    #pragma unroll
    for(int k=108;k<116;k++) lb[l*116+k] = 0;
  }

  // ---- f1: [16 x 108pad128] @ [128 x 32] = 8 MFMA ----
  f32x4 a1acc[2];
  {
    float b0v = prm[PT_B1F + l15], b1v = prm[PT_B1F + 16 + l15];
    a1acc[0] = f32x4{b0v,b0v,b0v,b0v};
    a1acc[1] = f32x4{b1v,b1v,b1v,b1v};
  }
  #pragma unroll
  for(int kc=0;kc<4;kc++){
    short8 af = (kc<3) ? mk_af16(lb, l15*116 + kc*32 + 4*g4)
                       : mk_af16_lo(lb, l15*116 + 96 + 4*g4);
    #pragma unroll
    for(int nt=0;nt<2;nt++){
      short8 bf = fsrc[(32+kc*2+nt)*64 + l];
      a1acc[nt] = __builtin_amdgcn_mfma_f32_16x16x32_bf16(af, bf, a1acc[nt], 0,0,0);
    }
  }
  {
    float m1[4], rs1[4];
    #pragma unroll
    for(int r=0;r<4;r++){
      float sm = a1acc[0][r] + a1acc[1][r];
      float sq = a1acc[0][r]*a1acc[0][r] + a1acc[1][r]*a1acc[1][r];
      #pragma unroll
      for(int st=1;st<16;st<<=1){ sm += __shfl_xor(sm,st); sq += __shfl_xor(sq,st); }
      float m = sm*(1.f/32.f);
      m1[r]=m; rs1[r]=frsq(sq*(1.f/32.f)-m*m+1e-5f);
    }
    #pragma unroll
    for(int nt=0;nt<2;nt++){
      float g  = prm[PT_G1F + nt*16 + l15];
      float be = prm[PT_BE1F + nt*16 + l15];
      #pragma unroll
      for(int r=0;r<4;r++){
        float vv = fmaxf((a1acc[nt][r]-m1[r])*rs1[r]*g + be, 0.f);
        lb[(4*g4+r)*116 + nt*16 + l15] = f2bf(vv);
      }
    }
  }

  // ---- f2: [16 x 32] @ [32 x 32] = 2 MFMA ----
  {
    f32x4 a2acc[2];
    float b0v = prm[PT_B2F + l15], b1v = prm[PT_B2F + 16 + l15];
    a2acc[0] = f32x4{b0v,b0v,b0v,b0v};
    a2acc[1] = f32x4{b1v,b1v,b1v,b1v};
    short8 af = mk_af16(lb, l15*116 + 4*g4);
    #pragma unroll
    for(int nt=0;nt<2;nt++){
      short8 bf = fsrc[(40+nt)*64 + l];
      a2acc[nt] = __builtin_amdgcn_mfma_f32_16x16x32_bf16(af, bf, a2acc[nt], 0,0,0);
    }
    float m1[4], rs1[4];
    #pragma unroll
    for(int r=0;r<4;r++){
      float sm = a2acc[0][r] + a2acc[1][r];
      float sq = a2acc[0][r]*a2acc[0][r] + a2acc[1][r]*a2acc[1][r];
      #pragma unroll
      for(int st=1;st<16;st<<=1){ sm += __shfl_xor(sm,st); sq += __shfl_xor(sq,st); }
      float m = sm*(1.f/32.f);
      m1[r]=m; rs1[r]=frsq(sq*(1.f/32.f)-m*m+1e-5f);
    }
    #pragma unroll
    for(int nt=0;nt<2;nt++){
      float g  = prm[PT_G2F + nt*16 + l15];
      float be = prm[PT_BE2F + nt*16 + l15];
      #pragma unroll
      for(int r=0;r<4;r++){
        float vv = fmaxf((a2acc[nt][r]-m1[r])*rs1[r]*g + be, 0.f);
        lb[(4*g4+r)*116 + nt*16 + l15] = f2bf(vv);
      }
    }
  }

  // ---- f3: [16 x 32] @ [32 x 102pad112] = 7 MFMA ----
  {
    f32x4 a3[7];
    float mskt[7];
    #pragma unroll
    for(int nt=0;nt<7;nt++){
      int n2 = nt*16 + l15;
      mskt[nt] = (n2 < 102) ? 1.f : 0.f;
      float bv = prm[PT_B3F + ((n2<102)?n2:0)] * mskt[nt];
      a3[nt] = f32x4{bv,bv,bv,bv};
    }
    short8 af = mk_af16(lb, l15*116 + 4*g4);
    #pragma unroll
    for(int nt=0;nt<7;nt++){
      short8 bf = fsrc[(42+nt)*64 + l];
      a3[nt] = __builtin_amdgcn_mfma_f32_16x16x32_bf16(af, bf, a3[nt], 0,0,0);
    }
    float mf[4], rsf[4];
    #pragma unroll
    for(int r=0;r<4;r++){
      float sm=0.f, sq=0.f;
      #pragma unroll
      for(int nt=0;nt<7;nt++){
        float vv = a3[nt][r];
        sm += mskt[nt]*vv; sq += mskt[nt]*vv*vv;
      }
      #pragma unroll
      for(int st=1;st<16;st<<=1){ sm += __shfl_xor(sm,st); sq += __shfl_xor(sq,st); }
      float m = sm*(1.f/102.f);
      mf[r]=m; rsf[r]=frsq(sq*(1.f/102.f)-m*m+1e-5f);
    }
    #pragma unroll
    for(int nt=0;nt<7;nt++){
      int n2 = nt*16 + l15;
      if(n2 < 102){
        float g  = prm[PT_G3F + n2];
        float be = prm[PT_BE3F + n2];
        #pragma unroll
        for(int r=0;r<4;r++){
          float val = sigmf((a3[nt][r]-mf[r])*rsf[r]*g + be);
          p.out[(size_t)(base + 4*g4 + r)*102 + n2] = val;
        }
      }
    }
  }
}

// ---------- AoS monolithic fallback (R1, proven) ----------
template<int IN>
DI void lstm_step(const float* __restrict__ Wih, const float* __restrict__ Whh,
                  const float* __restrict__ bih, const float* __restrict__ bhh,
                  const float* xin, const float* hin, float* c, float* hout){
  #pragma unroll
  for(int j=0;j<32;j++){
    float ai = bih[j]    + bhh[j];
    float af = bih[32+j] + bhh[32+j];
    float ag = bih[64+j] + bhh[64+j];
    float ao = bih[96+j] + bhh[96+j];
    #pragma unroll
    for(int k=0;k<IN;k++){
      float xv = xin[k];
      ai += xv*Wih[j*IN+k]; af += xv*Wih[(32+j)*IN+k];
      ag += xv*Wih[(64+j)*IN+k]; ao += xv*Wih[(96+j)*IN+k];
    }
    #pragma unroll
    for(int k=0;k<32;k++){
      float hv = hin[k];
      ai += hv*Whh[j*32+k]; af += hv*Whh[(32+j)*32+k];
      ag += hv*Whh[(64+j)*32+k]; ao += hv*Whh[(96+j)*32+k];
    }
    float cc = sigmf(af)*c[j] + sigmf(ai)*tanhf_(ag);
    c[j] = cc;
    hout[j] = sigmf(ao)*tanhf_(cc);
  }
}

__global__ __launch_bounds__(128,1) void csnet_mono(Params p){
  const int tid = threadIdx.x;
  const int b = blockIdx.x*128 + tid;
  const float* __restrict__ xr = p.x + (size_t)b*348;
  __shared__ float sbuf[128*103];
  float* my = &sbuf[tid*103];
  float h0[32], c0[32], h1[32], c1[32];
  #pragma unroll
  for(int j=0;j<32;j++){ h0[j]=0.f; c0[j]=0.f; h1[j]=0.f; c1[j]=0.f; }
  #pragma unroll 1
  for(int t=0;t<4;t++){
    float xt[3];
    #pragma unroll
    for(int d=0;d<3;d++) xt[d] = xr[220 + t*3 + d];
    float hA[32], hB[32];
    lstm_step<3 >(p.Wih0,p.Whh0,p.bih0,p.bhh0, xt, h0, c0, hA);
    lstm_step<32>(p.Wih1,p.Whh1,p.bih1,p.bhh1, hA, h1, c1, hB);
    #pragma unroll
    for(int j=0;j<32;j++){ h0[j]=hA[j]; h1[j]=hB[j]; }
  }
  float pp[3], vel[3];
  #pragma unroll
  for(int d=0;d<3;d++){
    float a = p.fcb[d];
    #pragma unroll
    for(int j=0;j<32;j++) a += h1[j]*p.fcW[d*32+j];
    pp[d]  = a;
    vel[d] = (a - xr[229+d])*10.f;
  }
  float s1 = 0.f, s2 = 0.f;
  for(int w=0; w<102; ++w){
    #pragma unroll
    for(int o=0;o<4;o++){
      float s = p.b2[o];
      #pragma unroll
      for(int r=0;r<3;r++)
        #pragma unroll
        for(int kk=0;kk<5;kk++){
          int c = w - 2 + kk;
          float v = (c>=0 && c<=101) ? xr[r*116 + 1 + (c<0?0:(c>101?101:c))] : 0.f;
          s += v*p.W2[o*15 + r*5 + kk];
        }
      s1 += s; s2 += s*s;
    }
  }
  float m2  = s1*(1.f/408.f);
  float rs2 = frsq(s2*(1.f/408.f) - m2*m2 + 1e-5f);
  float s31=0.f, s32=0.f;
  for(int w=0; w<102; ++w){
    float o3 = p.b3[0];
    #pragma unroll
    for(int o=0;o<4;o++){
      float s = p.b2[o];
      #pragma unroll
      for(int r=0;r<3;r++)
        #pragma unroll
        for(int kk=0;kk<5;kk++){
          int c = w - 2 + kk;
          float v = (c>=0 && c<=101) ? xr[r*116 + 1 + (c<0?0:(c>101?101:c))] : 0.f;
          s += v*p.W2[o*15 + r*5 + kk];
        }
      float nv = (s - m2)*rs2*p.g2[o*102+w] + p.be2[o*102+w];
      o3 += fmaxf(nv, 0.f)*p.W3[o];
    }
    s31 += o3; s32 += o3*o3;
    my[w] = o3;
  }
  float m3  = s31*(1.f/102.f);
  float rs3 = frsq(s32*(1.f/102.f) - m3*m3 + 1e-5f);
  float a1[32];
  #pragma unroll
  for(int j=0;j<32;j++) a1[j] = p.b1f[j];
  for(int w=0; w<102; ++w){
    float v = fmaxf((my[w]-m3)*rs3*p.g3[w] + p.be3[w], 0.f);
    #pragma unroll
    for(int j=0;j<32;j++) a1[j] += v*p.W1f[j*108+w];
  }
  #pragma unroll
  for(int d=0;d<3;d++)
    #pragma unroll
    for(int j=0;j<32;j++){
      a1[j] += pp[d]*p.W1f[j*108+102+d];
      a1[j] += vel[d]*p.W1f[j*108+105+d];
    }
  {
    float s=0.f,qq=0.f;
    #pragma unroll
    for(int j=0;j<32;j++){ s+=a1[j]; qq+=a1[j]*a1[j]; }
    float m=s*(1.f/32.f), rs=frsq(qq*(1.f/32.f)-m*m+1e-5f);
    #pragma unroll
    for(int j=0;j<32;j++) a1[j]=fmaxf((a1[j]-m)*rs*p.g1f[j]+p.be1f[j],0.f);
  }
  float a2[32];
  #pragma unroll
  for(int j=0;j<32;j++){
    float a = p.b2f[j];
    #pragma unroll
    for(int k=0;k<32;k++) a += a1[k]*p.W2f[j*32+k];
    a2[j]=a;
  }
  {
    float s=0.f,qq=0.f;
    #pragma unroll
    for(int j=0;j<32;j++){ s+=a2[j]; qq+=a2[j]*a2[j]; }
    float m=s*(1.f/32.f), rs=frsq(qq*(1.f/32.f)-m*m+1e-5f);
    #pragma unroll
    for(int j=0;j<32;j++) a2[j]=fmaxf((a2[j]-m)*rs*p.g2f[j]+p.be2f[j],0.f);
  }
  float t1=0.f,t2=0.f;
  for(int w=0;w<102;++w){
    float a = p.b3f[w];
    #pragma unroll
    for(int j=0;j<32;j++) a += a2[j]*p.W3f[w*32+j];
    t1+=a; t2+=a*a;
    my[w]=a;
  }
  float mf=t1*(1.f/102.f), rsf=frsq(t2*(1.f/102.f)-mf*mf+1e-5f);
  for(int w=0;w<102;++w) my[w]=sigmf((my[w]-mf)*rsf*p.g3f[w]+p.be3f[w]);
  __syncthreads();
  float* op = p.out + (size_t)blockIdx.x*13056;
  #pragma unroll 1
  for(int m=0;m<26;m++){
    int i4 = tid + 128*m;
    if(i4 < 3264){
      int i0=i4*4;
      float4 v;
      #pragma unroll
      for(int ee=0;ee<4;ee++){
        int idx=i0+ee; int sm=idx/102; int wd=idx-sm*102;
        ((float*)&v)[ee]=sbuf[sm*103+wd];
      }
      *reinterpret_cast<float4*>(op+i0)=v;
    }
  }
}

extern "C" void kernel_launch(void* const* d_in, const int* in_sizes, int n_in,
                              void* d_out, int out_size, void* d_ws, size_t ws_size,
                              hipStream_t stream) {
  (void)in_sizes; (void)n_in; (void)out_size;
  Params p;
  p.x    = (const float*)d_in[0];
  p.Wih0 = (const float*)d_in[1];  p.Whh0 = (const float*)d_in[2];
  p.bih0 = (const float*)d_in[3];  p.bhh0 = (const float*)d_in[4];
  p.Wih1 = (const float*)d_in[5];  p.Whh1 = (const float*)d_in[6];
  p.bih1 = (const float*)d_in[7];  p.bhh1 = (const float*)d_in[8];
  p.fcW  = (const float*)d_in[9];  p.fcb  = (const float*)d_in[10];
  p.W2   = (const float*)d_in[11]; p.b2   = (const float*)d_in[12];
  p.g2   = (const float*)d_in[13]; p.be2  = (const float*)d_in[14];
  p.W3   = (const float*)d_in[15]; p.b3   = (const float*)d_in[16];
  p.g3   = (const float*)d_in[17]; p.be3  = (const float*)d_in[18];
  p.W1f  = (const float*)d_in[19]; p.b1f  = (const float*)d_in[20];
  p.g1f  = (const float*)d_in[21]; p.be1f = (const float*)d_in[22];
  p.W2f  = (const float*)d_in[23]; p.b2f  = (const float*)d_in[24];
  p.g2f  = (const float*)d_in[25]; p.be2f = (const float*)d_in[26];
  p.W3f  = (const float*)d_in[27]; p.b3f  = (const float*)d_in[28];
  p.g3f  = (const float*)d_in[29]; p.be3f = (const float*)d_in[30];
  p.out  = (float*)d_out;

  // ws layout (floats): pv[6*N] | bsum[256] | ptail[1518] | frags (u16)
  const size_t PV_F   = (size_t)6*NSAMP;
  const size_t BS_F   = 256;
  const size_t FRAG_BYTES = (size_t)NFRAG*64*8*2;
  const size_t head_f = PV_F + BS_F + PT_N;
  const size_t need = head_f*4 + FRAG_BYTES;

  if(ws_size >= need){
    float* pv    = (float*)d_ws;
    float* bsum  = pv + PV_F;
    float* ptail = bsum + BS_F;
    unsigned short* frags = (unsigned short*)(ptail + PT_N);
    p.pv = pv; p.ptail = ptail; p.frags = frags;
    prep_kernel<<<1, 256, 0, stream>>>(p, frags, bsum, ptail);
    lstm_kernel<<<NSAMP/64, 256, 0, stream>>>(p.x, frags, bsum, p.fcW, p.fcb, pv);
    tail_kernel<<<NSAMP/64, 256, 0, stream>>>(p);
  } else {
    p.pv = nullptr; p.ptail = nullptr; p.frags = nullptr;
    csnet_mono<<<NSAMP/128, 128, 0, stream>>>(p);
  }
}

// Round 12
// 118.571 us; speedup vs baseline: 4.2615x; 1.0776x over previous
//
#include <hip/hip_runtime.h>

#define DI __device__ __forceinline__
#define NSAMP 65536

typedef __attribute__((ext_vector_type(4))) float f32x4;
typedef __attribute__((ext_vector_type(8))) short short8;
typedef __attribute__((ext_vector_type(4))) short short4v;

DI float frcp(float x){ return __builtin_amdgcn_rcpf(x); }
DI float frsq(float x){ return __builtin_amdgcn_rsqf(x); }
DI float sigmf(float x){ return frcp(1.f + __expf(-x)); }
DI float tanhf_(float x){ return 1.f - 2.f*frcp(__expf(2.f*x) + 1.f); }
DI unsigned short f2bf(float f){                 // RNE float->bf16
  unsigned u = __float_as_uint(f);
  return (unsigned short)((u + 0x7FFFu + ((u>>16)&1u)) >> 16);
}
DI float bf2f(unsigned short h){ return __uint_as_float(((unsigned)h)<<16); }

struct Params {
  const float* __restrict__ x;
  const float* __restrict__ pv;    // [6][NSAMP] (ws)
  const float* __restrict__ ptail; // gathered small params [1518] (ws)
  const unsigned short* __restrict__ frags;
  const float* __restrict__ Wih0; const float* __restrict__ Whh0;
  const float* __restrict__ bih0; const float* __restrict__ bhh0;
  const float* __restrict__ Wih1; const float* __restrict__ Whh1;
  const float* __restrict__ bih1; const float* __restrict__ bhh1;
  const float* __restrict__ fcW;  const float* __restrict__ fcb;
  const float* __restrict__ W2;   const float* __restrict__ b2;
  const float* __restrict__ g2;   const float* __restrict__ be2;
  const float* __restrict__ W3;   const float* __restrict__ b3;
  const float* __restrict__ g3;   const float* __restrict__ be3;
  const float* __restrict__ W1f;  const float* __restrict__ b1f;
  const float* __restrict__ g1f;  const float* __restrict__ be1f;
  const float* __restrict__ W2f;  const float* __restrict__ b2f;
  const float* __restrict__ g2f;  const float* __restrict__ be2f;
  const float* __restrict__ W3f;  const float* __restrict__ b3f;
  const float* __restrict__ g3f;  const float* __restrict__ be3f;
  float* __restrict__ out;
};

// ptail offsets (floats)
#define PT_G2   0
#define PT_BE2  408
#define PT_G3   816
#define PT_BE3  918
#define PT_B1F  1020
#define PT_G1F  1052
#define PT_BE1F 1084
#define PT_B2F  1116
#define PT_G2F  1148
#define PT_BE2F 1180
#define PT_B3F  1212
#define PT_G3F  1314
#define PT_BE3F 1416
#define PT_N    1518
#define NFRAG   49

// ---------- prep: all weight B-fragments (bf16) + bias sums + param gather ----------
__global__ __launch_bounds__(256,1) void prep_kernel(Params p,
    unsigned short* __restrict__ frags, float* __restrict__ bsum,
    float* __restrict__ ptail){
  const int tid = threadIdx.x;
  if(tid < 64){
    const int l15 = tid & 15, g4 = tid >> 4;
    const float* mats[3] = {p.Whh0, p.Wih1, p.Whh1};
    for(int m=0;m<3;m++)
      for(int t=0;t<8;t++){
        const int n = 16*t + l15;
        unsigned short* dst = &frags[((size_t)(m*8+t)*64 + tid)*8];
        for(int j=0;j<4;j++){
          dst[j]   = f2bf(mats[m][n*32 + 4*g4 + j]);
          dst[4+j] = f2bf(mats[m][n*32 + 16 + 4*g4 + j]);
        }
      }
    for(int t=0;t<8;t++){
      const int n = 16*t + l15;
      unsigned short* dst = &frags[((size_t)(24+t)*64 + tid)*8];
      for(int j=0;j<4;j++){
        int k = 4*g4 + j;
        dst[j]   = (k < 3) ? f2bf(p.Wih0[n*3 + k]) : (unsigned short)0;
        dst[4+j] = 0;
      }
    }
    // f1: [108pad128][32] from W1f[32][108] -> idx 32 + kc*2 + nt
    for(int kc=0;kc<4;kc++)
      for(int nt=0;nt<2;nt++){
        const int n = nt*16 + l15;
        unsigned short* dst = &frags[((size_t)(32+kc*2+nt)*64 + tid)*8];
        for(int j=0;j<4;j++){
          int k0 = kc*32 + 4*g4 + j;
          int k1 = kc*32 + 16 + 4*g4 + j;
          dst[j]   = (k0<108) ? f2bf(p.W1f[n*108+k0]) : (unsigned short)0;
          dst[4+j] = (k1<108) ? f2bf(p.W1f[n*108+k1]) : (unsigned short)0;
        }
      }
    // f2: [32][32] -> idx 40+nt
    for(int nt=0;nt<2;nt++){
      const int n = nt*16 + l15;
      unsigned short* dst = &frags[((size_t)(40+nt)*64 + tid)*8];
      for(int j=0;j<4;j++){
        dst[j]   = f2bf(p.W2f[n*32 + 4*g4 + j]);
        dst[4+j] = f2bf(p.W2f[n*32 + 16 + 4*g4 + j]);
      }
    }
    // f3: [32][102pad112] -> idx 42+nt (7 tiles)
    for(int nt=0;nt<7;nt++){
      const int n2 = nt*16 + l15;
      unsigned short* dst = &frags[((size_t)(42+nt)*64 + tid)*8];
      for(int j=0;j<4;j++){
        int k0 = 4*g4 + j, k1 = 16 + 4*g4 + j;
        dst[j]   = (n2<102) ? f2bf(p.W3f[n2*32+k0]) : (unsigned short)0;
        dst[4+j] = (n2<102) ? f2bf(p.W3f[n2*32+k1]) : (unsigned short)0;
      }
    }
  } else if(tid < 192){
    int i = tid - 64;
    bsum[i]       = p.bih0[i] + p.bhh0[i];
    bsum[128 + i] = p.bih1[i] + p.bhh1[i];
  }
  for(int i=tid;i<408;i+=256){ ptail[PT_G2+i]=p.g2[i]; ptail[PT_BE2+i]=p.be2[i]; }
  for(int i=tid;i<102;i+=256){
    ptail[PT_G3+i]=p.g3[i];   ptail[PT_BE3+i]=p.be3[i];
    ptail[PT_B3F+i]=p.b3f[i]; ptail[PT_G3F+i]=p.g3f[i]; ptail[PT_BE3F+i]=p.be3f[i];
  }
  if(tid<32){
    ptail[PT_B1F+tid]=p.b1f[tid];   ptail[PT_G1F+tid]=p.g1f[tid];
    ptail[PT_BE1F+tid]=p.be1f[tid]; ptail[PT_B2F+tid]=p.b2f[tid];
    ptail[PT_G2F+tid]=p.g2f[tid];   ptail[PT_BE2F+tid]=p.be2f[tid];
  }
}

// A-frag from fp32 LDS (lstm h-buffer [16][36])
DI short8 mk_afrag(const float* hbase, int l15, int g4){
  const float4* p0 = (const float4*)(hbase + l15*36 + 4*g4);
  const float4* p1 = (const float4*)(hbase + l15*36 + 16 + 4*g4);
  float4 lo = *p0; float4 hi = *p1;
  short8 s;
  s[0]=(short)f2bf(lo.x); s[1]=(short)f2bf(lo.y); s[2]=(short)f2bf(lo.z); s[3]=(short)f2bf(lo.w);
  s[4]=(short)f2bf(hi.x); s[5]=(short)f2bf(hi.y); s[6]=(short)f2bf(hi.z); s[7]=(short)f2bf(hi.w);
  return s;
}
// A-frag from bf16 LDS, element offset off
DI short8 mk_af16(const unsigned short* lb, int off){
  short4v lo = *(const short4v*)(lb + off);
  short4v hi = *(const short4v*)(lb + off + 16);
  short8 s;
  s[0]=lo[0]; s[1]=lo[1]; s[2]=lo[2]; s[3]=lo[3];
  s[4]=hi[0]; s[5]=hi[1]; s[6]=hi[2]; s[7]=hi[3];
  return s;
}
DI short8 mk_af16_lo(const unsigned short* lb, int off){
  short4v lo = *(const short4v*)(lb + off);
  short8 s;
  s[0]=lo[0]; s[1]=lo[1]; s[2]=lo[2]; s[3]=lo[3];
  s[4]=0; s[5]=0; s[6]=0; s[7]=0;
  return s;
}

// ---------- LSTM via MFMA: 1 wave = 16 samples (unchanged, proven) ----------
__global__ __launch_bounds__(256,1) void lstm_kernel(
    const float* __restrict__ x, const unsigned short* __restrict__ frags,
    const float* __restrict__ bsum, const float* __restrict__ fcW,
    const float* __restrict__ fcb, float* __restrict__ pv){
  __shared__ float hb[4][2][16][36];
  const int tid = threadIdx.x;
  const int w = tid >> 6, l = tid & 63;
  const int l15 = l & 15, g4 = l >> 4;
  const int base = blockIdx.x*64 + w*16;
  const float* __restrict__ xrow = x + (size_t)(base + l15)*348;

  short8 wf[4][8];
  const short8* fsrc = (const short8*)frags;
  #pragma unroll
  for(int m=0;m<4;m++)
    #pragma unroll
    for(int t=0;t<8;t++) wf[m][t] = fsrc[(m*8+t)*64 + l];

  float bfr[2][8];
  #pragma unroll
  for(int t=0;t<8;t++){
    bfr[0][t] = bsum[16*t + l15];
    bfr[1][t] = bsum[128 + 16*t + l15];
  }
  #pragma unroll
  for(int half=0; half<2; half++)
    #pragma unroll
    for(int r=0;r<4;r++){
      hb[w][0][g4*4+r][l15+16*half] = 0.f;
      hb[w][1][g4*4+r][l15+16*half] = 0.f;
    }
  float c0[8], c1[8];
  #pragma unroll
  for(int i=0;i<8;i++){ c0[i]=0.f; c1[i]=0.f; }

  #pragma unroll 1
  for(int t=0;t<4;t++){
    short8 ax;
    {
      float xv0 = xrow[220 + t*3 + 0];
      float xv1 = xrow[220 + t*3 + 1];
      float xv2 = xrow[220 + t*3 + 2];
      bool gz = (g4 == 0);
      ax[0] = gz ? (short)f2bf(xv0) : (short)0;
      ax[1] = gz ? (short)f2bf(xv1) : (short)0;
      ax[2] = gz ? (short)f2bf(xv2) : (short)0;
      ax[3]=0; ax[4]=0; ax[5]=0; ax[6]=0; ax[7]=0;
    }
    short8 ah0 = mk_afrag(&hb[w][0][0][0], l15, g4);
    f32x4 acc0[8];
    #pragma unroll
    for(int n=0;n<8;n++){
      f32x4 a; a[0]=bfr[0][n]; a[1]=bfr[0][n]; a[2]=bfr[0][n]; a[3]=bfr[0][n];
      a = __builtin_amdgcn_mfma_f32_16x16x32_bf16(ax,  wf[3][n], a, 0,0,0);
      a = __builtin_amdgcn_mfma_f32_16x16x32_bf16(ah0, wf[0][n], a, 0,0,0);
      acc0[n] = a;
    }
    #pragma unroll
    for(int half=0; half<2; half++)
      #pragma unroll
      for(int r=0;r<4;r++){
        float gi = acc0[0+half][r], gf = acc0[2+half][r];
        float gg = acc0[4+half][r], go = acc0[6+half][r];
        float cc = sigmf(gf)*c0[half*4+r] + sigmf(gi)*tanhf_(gg);
        c0[half*4+r] = cc;
        hb[w][0][g4*4+r][l15+16*half] = sigmf(go)*tanhf_(cc);
      }
    short8 ah0n = mk_afrag(&hb[w][0][0][0], l15, g4);
    short8 ah1  = mk_afrag(&hb[w][1][0][0], l15, g4);
    f32x4 acc1[8];
    #pragma unroll
    for(int n=0;n<8;n++){
      f32x4 a; a[0]=bfr[1][n]; a[1]=bfr[1][n]; a[2]=bfr[1][n]; a[3]=bfr[1][n];
      a = __builtin_amdgcn_mfma_f32_16x16x32_bf16(ah0n, wf[1][n], a, 0,0,0);
      a = __builtin_amdgcn_mfma_f32_16x16x32_bf16(ah1,  wf[2][n], a, 0,0,0);
      acc1[n] = a;
    }
    #pragma unroll
    for(int half=0; half<2; half++)
      #pragma unroll
      for(int r=0;r<4;r++){
        float gi = acc1[0+half][r], gf = acc1[2+half][r];
        float gg = acc1[4+half][r], go = acc1[6+half][r];
        float cc = sigmf(gf)*c1[half*4+r] + sigmf(gi)*tanhf_(gg);
        c1[half*4+r] = cc;
        hb[w][1][g4*4+r][l15+16*half] = sigmf(go)*tanhf_(cc);
      }
  }
  if(l < 16){
    const int gs = base + l;
    const float* xr2 = x + (size_t)gs*348;
    #pragma unroll
    for(int d=0;d<3;d++){
      float a = fcb[d];
      #pragma unroll
      for(int u=0;u<32;u++) a += hb[w][1][l][u]*fcW[d*32+u];
      float pr = xr2[229 + d];
      pv[(size_t)d*NSAMP + gs]     = a;
      pv[(size_t)(3+d)*NSAMP + gs] = (a - pr)*10.f;
    }
  }
}

DI float rg4(float v){       // reduce across the 4 g4 groups (same l15)
  v += __shfl_xor(v, 16);
  v += __shfl_xor(v, 32);
  return v;
}

// ---------- tail: single-pass conv (packed bf16 o2 in regs) + MFMA FC ----------
__global__ __launch_bounds__(256,1) void tail_kernel(Params p){
  __shared__ float prm[PT_N];
  __shared__ unsigned int xs32[64*175];    // bf16 x rows [64][348pad350], 44.8 KB
  const int tid = threadIdx.x;
  const int w = tid >> 6, l = tid & 63;
  const int l15 = l & 15, g4 = l >> 4;
  const int base = blockIdx.x*64 + w*16;
  const int sl   = w*16 + l15;             // block-local sample
  // lb overlays this wave's xs region (928 u32 needed of 2800)
  unsigned short* lb = (unsigned short*)(xs32 + w*16*175);
  const short8* fsrc = (const short8*)p.frags;
  const unsigned short* xsp = (const unsigned short*)xs32;

  for(int i=tid;i<PT_N;i+=256) prm[i]=p.ptail[i];
  // stage 64 x-rows, coalesced float4 -> packed bf16 (row stride 175 u32)
  {
    const float4* src = reinterpret_cast<const float4*>(p.x + (size_t)blockIdx.x*64*348);
    #pragma unroll 1
    for(int i=tid; i<64*87; i+=256){
      float4 v = src[i];
      int smp = i/87; int off = i - smp*87;
      unsigned lo = (unsigned)f2bf(v.x) | ((unsigned)f2bf(v.y)<<16);
      unsigned hi = (unsigned)f2bf(v.z) | ((unsigned)f2bf(v.w)<<16);
      xs32[smp*175 + off*2]     = lo;
      xs32[smp*175 + off*2 + 1] = hi;
    }
  }
  __syncthreads();

  // csi element read: xs[sl][r*116+1+c] as bf16
  #define LDX(r,c) bf2f(xsp[sl*350 + (r)*116 + 1 + (c)])

  const int C0   = g4*26;
  const int ncol = (g4==3) ? 24 : 26;

  // ---- SINGLE conv pass: o2 (4 ch/col) packed bf16 in regs + LN2 stats ----
  unsigned o2p[52];                        // col i: [2i]=(ch0,ch1) [2i+1]=(ch2,ch3)
  float s1=0.f, s2=0.f;
  {
    float u0[3],u1[3],u2[3],u3[3],u4[3];
    #pragma unroll
    for(int r=0;r<3;r++){
      u0[r] = (C0-2 >= 0) ? LDX(r, C0-2) : 0.f;
      u1[r] = (C0-1 >= 0) ? LDX(r, C0-1) : 0.f;
      u2[r] = LDX(r, C0);
      u3[r] = LDX(r, C0+1);
      u4[r] = LDX(r, C0+2);
    }
    #pragma unroll
    for(int i=0;i<26;i++){
      float msk = (i < ncol) ? 1.f : 0.f;
      float sv[4];
      #pragma unroll
      for(int o=0;o<4;o++){
        float s = p.b2[o];
        #pragma unroll
        for(int r=0;r<3;r++)
          s += u0[r]*p.W2[o*15+r*5+0]+u1[r]*p.W2[o*15+r*5+1]+u2[r]*p.W2[o*15+r*5+2]
             + u3[r]*p.W2[o*15+r*5+3]+u4[r]*p.W2[o*15+r*5+4];
        sv[o] = s;
        s1 += msk*s; s2 += msk*s*s;
      }
      o2p[2*i]   = (unsigned)f2bf(sv[0]) | ((unsigned)f2bf(sv[1])<<16);
      o2p[2*i+1] = (unsigned)f2bf(sv[2]) | ((unsigned)f2bf(sv[3])<<16);
      int pn = C0 + i + 3;
      int pc = (pn <= 101) ? pn : 101;
      #pragma unroll
      for(int r=0;r<3;r++){
        float nv = LDX(r, pc);
        nv = (pn <= 101) ? nv : 0.f;
        u0[r]=u1[r]; u1[r]=u2[r]; u2[r]=u3[r]; u3[r]=u4[r]; u4[r]=nv;
      }
    }
  }
  #undef LDX
  float m2  = rg4(s1)*(1.f/408.f);
  float va2 = rg4(s2)*(1.f/408.f) - m2*m2;
  float rs2 = frsq(va2 + 1e-5f);

  // ---- pass 2 from registers: LN2/relu + cv3 -> o3r[26], LN3 stats ----
  float o3r[26];
  float s31=0.f, s32=0.f;
  {
    float b3v = p.b3[0];
    float w3v[4];
    #pragma unroll
    for(int o=0;o<4;o++) w3v[o] = p.W3[o];
    #pragma unroll
    for(int i=0;i<26;i++){
      const int wc = (C0+i <= 101) ? C0+i : 101;
      float msk = (i < ncol) ? 1.f : 0.f;
      float sv[4];
      sv[0] = bf2f((unsigned short)(o2p[2*i]    & 0xffffu));
      sv[1] = bf2f((unsigned short)(o2p[2*i]   >> 16));
      sv[2] = bf2f((unsigned short)(o2p[2*i+1]  & 0xffffu));
      sv[3] = bf2f((unsigned short)(o2p[2*i+1] >> 16));
      float o3 = b3v;
      #pragma unroll
      for(int o=0;o<4;o++){
        float nv = (sv[o] - m2)*rs2*prm[PT_G2+o*102+wc] + prm[PT_BE2+o*102+wc];
        o3 += fmaxf(nv, 0.f)*w3v[o];
      }
      s31 += msk*o3; s32 += msk*o3*o3;
      o3r[i] = o3;
    }
  }
  float m3  = rg4(s31)*(1.f/102.f);
  float va3 = rg4(s32)*(1.f/102.f) - m3*m3;
  float rs3 = frsq(va3 + 1e-5f);

  // xs region for THIS WAVE is now dead -> safe to write lb overlay.
  // LN3 + relu -> lb[sample=l15][col] bf16
  #pragma unroll
  for(int i=0;i<26;i++){
    if(i < ncol){
      const int wc = C0 + i;
      float v = fmaxf((o3r[i]-m3)*rs3*prm[PT_G3+wc] + prm[PT_BE3+wc], 0.f);
      lb[l15*116 + wc] = f2bf(v);
    }
  }
  // pp/vel into lb slots 102..107, zero 108..115
  if(l < 16){
    #pragma unroll
    for(int d=0;d<3;d++){
      lb[l*116+102+d] = f2bf(p.pv[(size_t)d*NSAMP + base + l]);
      lb[l*116+105+d] = f2bf(p.pv[(size_t)(3+d)*NSAMP + base + l]);
    }
    #pragma unroll
    for(int k=108;k<116;k++) lb[l*116+k] = 0;
  }

  // ---- f1: [16 x 108pad128] @ [128 x 32] = 8 MFMA ----
  f32x4 a1acc[2];
  {
    float b0v = prm[PT_B1F + l15], b1v = prm[PT_B1F + 16 + l15];
    a1acc[0] = f32x4{b0v,b0v,b0v,b0v};
    a1acc[1] = f32x4{b1v,b1v,b1v,b1v};
  }
  #pragma unroll
  for(int kc=0;kc<4;kc++){
    short8 af = (kc<3) ? mk_af16(lb, l15*116 + kc*32 + 4*g4)
                       : mk_af16_lo(lb, l15*116 + 96 + 4*g4);
    #pragma unroll
    for(int nt=0;nt<2;nt++){
      short8 bf = fsrc[(32+kc*2+nt)*64 + l];
      a1acc[nt] = __builtin_amdgcn_mfma_f32_16x16x32_bf16(af, bf, a1acc[nt], 0,0,0);
    }
  }
  {
    float m1[4], rs1[4];
    #pragma unroll
    for(int r=0;r<4;r++){
      float sm = a1acc[0][r] + a1acc[1][r];
      float sq = a1acc[0][r]*a1acc[0][r] + a1acc[1][r]*a1acc[1][r];
      #pragma unroll
      for(int st=1;st<16;st<<=1){ sm += __shfl_xor(sm,st); sq += __shfl_xor(sq,st); }
      float m = sm*(1.f/32.f);
      m1[r]=m; rs1[r]=frsq(sq*(1.f/32.f)-m*m+1e-5f);
    }
    #pragma unroll
    for(int nt=0;nt<2;nt++){
      float g  = prm[PT_G1F + nt*16 + l15];
      float be = prm[PT_BE1F + nt*16 + l15];
      #pragma unroll
      for(int r=0;r<4;r++){
        float vv = fmaxf((a1acc[nt][r]-m1[r])*rs1[r]*g + be, 0.f);
        lb[(4*g4+r)*116 + nt*16 + l15] = f2bf(vv);
      }
    }
  }

  // ---- f2: [16 x 32] @ [32 x 32] = 2 MFMA ----
  {
    f32x4 a2acc[2];
    float b0v = prm[PT_B2F + l15], b1v = prm[PT_B2F + 16 + l15];
    a2acc[0] = f32x4{b0v,b0v,b0v,b0v};
    a2acc[1] = f32x4{b1v,b1v,b1v,b1v};
    short8 af = mk_af16(lb, l15*116 + 4*g4);
    #pragma unroll
    for(int nt=0;nt<2;nt++){
      short8 bf = fsrc[(40+nt)*64 + l];
      a2acc[nt] = __builtin_amdgcn_mfma_f32_16x16x32_bf16(af, bf, a2acc[nt], 0,0,0);
    }
    float m1[4], rs1[4];
    #pragma unroll
    for(int r=0;r<4;r++){
      float sm = a2acc[0][r] + a2acc[1][r];
      float sq = a2acc[0][r]*a2acc[0][r] + a2acc[1][r]*a2acc[1][r];
      #pragma unroll
      for(int st=1;st<16;st<<=1){ sm += __shfl_xor(sm,st); sq += __shfl_xor(sq,st); }
      float m = sm*(1.f/32.f);
      m1[r]=m; rs1[r]=frsq(sq*(1.f/32.f)-m*m+1e-5f);
    }
    #pragma unroll
    for(int nt=0;nt<2;nt++){
      float g  = prm[PT_G2F + nt*16 + l15];
      float be = prm[PT_BE2F + nt*16 + l15];
      #pragma unroll
      for(int r=0;r<4;r++){
        float vv = fmaxf((a2acc[nt][r]-m1[r])*rs1[r]*g + be, 0.f);
        lb[(4*g4+r)*116 + nt*16 + l15] = f2bf(vv);
      }
    }
  }

  // ---- f3: [16 x 32] @ [32 x 102pad112] = 7 MFMA ----
  {
    f32x4 a3[7];
    float mskt[7];
    #pragma unroll
    for(int nt=0;nt<7;nt++){
      int n2 = nt*16 + l15;
      mskt[nt] = (n2 < 102) ? 1.f : 0.f;
      float bv = prm[PT_B3F + ((n2<102)?n2:0)] * mskt[nt];
      a3[nt] = f32x4{bv,bv,bv,bv};
    }
    short8 af = mk_af16(lb, l15*116 + 4*g4);
    #pragma unroll
    for(int nt=0;nt<7;nt++){
      short8 bf = fsrc[(42+nt)*64 + l];
      a3[nt] = __builtin_amdgcn_mfma_f32_16x16x32_bf16(af, bf, a3[nt], 0,0,0);
    }
    float mf[4], rsf[4];
    #pragma unroll
    for(int r=0;r<4;r++){
      float sm=0.f, sq=0.f;
      #pragma unroll
      for(int nt=0;nt<7;nt++){
        float vv = a3[nt][r];
        sm += mskt[nt]*vv; sq += mskt[nt]*vv*vv;
      }
      #pragma unroll
      for(int st=1;st<16;st<<=1){ sm += __shfl_xor(sm,st); sq += __shfl_xor(sq,st); }
      float m = sm*(1.f/102.f);
      mf[r]=m; rsf[r]=frsq(sq*(1.f/102.f)-m*m+1e-5f);
    }
    #pragma unroll
    for(int nt=0;nt<7;nt++){
      int n2 = nt*16 + l15;
      if(n2 < 102){
        float g  = prm[PT_G3F + n2];
        float be = prm[PT_BE3F + n2];
        #pragma unroll
        for(int r=0;r<4;r++){
          float val = sigmf((a3[nt][r]-mf[r])*rsf[r]*g + be);
          p.out[(size_t)(base + 4*g4 + r)*102 + n2] = val;
        }
      }
    }
  }
}

// ---------- AoS monolithic fallback (R1, proven) ----------
template<int IN>
DI void lstm_step(const float* __restrict__ Wih, const float* __restrict__ Whh,
                  const float* __restrict__ bih, const float* __restrict__ bhh,
                  const float* xin, const float* hin, float* c, float* hout){
  #pragma unroll
  for(int j=0;j<32;j++){
    float ai = bih[j]    + bhh[j];
    float af = bih[32+j] + bhh[32+j];
    float ag = bih[64+j] + bhh[64+j];
    float ao = bih[96+j] + bhh[96+j];
    #pragma unroll
    for(int k=0;k<IN;k++){
      float xv = xin[k];
      ai += xv*Wih[j*IN+k]; af += xv*Wih[(32+j)*IN+k];
      ag += xv*Wih[(64+j)*IN+k]; ao += xv*Wih[(96+j)*IN+k];
    }
    #pragma unroll
    for(int k=0;k<32;k++){
      float hv = hin[k];
      ai += hv*Whh[j*32+k]; af += hv*Whh[(32+j)*32+k];
      ag += hv*Whh[(64+j)*32+k]; ao += hv*Whh[(96+j)*32+k];
    }
    float cc = sigmf(af)*c[j] + sigmf(ai)*tanhf_(ag);
    c[j] = cc;
    hout[j] = sigmf(ao)*tanhf_(cc);
  }
}

__global__ __launch_bounds__(128,1) void csnet_mono(Params p){
  const int tid = threadIdx.x;
  const int b = blockIdx.x*128 + tid;
  const float* __restrict__ xr = p.x + (size_t)b*348;
  __shared__ float sbuf[128*103];
  float* my = &sbuf[tid*103];
  float h0[32], c0[32], h1[32], c1[32];
  #pragma unroll
  for(int j=0;j<32;j++){ h0[j]=0.f; c0[j]=0.f; h1[j]=0.f; c1[j]=0.f; }
  #pragma unroll 1
  for(int t=0;t<4;t++){
    float xt[3];
    #pragma unroll
    for(int d=0;d<3;d++) xt[d] = xr[220 + t*3 + d];
    float hA[32], hB[32];
    lstm_step<3 >(p.Wih0,p.Whh0,p.bih0,p.bhh0, xt, h0, c0, hA);
    lstm_step<32>(p.Wih1,p.Whh1,p.bih1,p.bhh1, hA, h1, c1, hB);
    #pragma unroll
    for(int j=0;j<32;j++){ h0[j]=hA[j]; h1[j]=hB[j]; }
  }
  float pp[3], vel[3];
  #pragma unroll
  for(int d=0;d<3;d++){
    float a = p.fcb[d];
    #pragma unroll
    for(int j=0;j<32;j++) a += h1[j]*p.fcW[d*32+j];
    pp[d]  = a;
    vel[d] = (a - xr[229+d])*10.f;
  }
  float s1 = 0.f, s2 = 0.f;
  for(int w=0; w<102; ++w){
    #pragma unroll
    for(int o=0;o<4;o++){
      float s = p.b2[o];
      #pragma unroll
      for(int r=0;r<3;r++)
        #pragma unroll
        for(int kk=0;kk<5;kk++){
          int c = w - 2 + kk;
          float v = (c>=0 && c<=101) ? xr[r*116 + 1 + (c<0?0:(c>101?101:c))] : 0.f;
          s += v*p.W2[o*15 + r*5 + kk];
        }
      s1 += s; s2 += s*s;
    }
  }
  float m2  = s1*(1.f/408.f);
  float rs2 = frsq(s2*(1.f/408.f) - m2*m2 + 1e-5f);
  float s31=0.f, s32=0.f;
  for(int w=0; w<102; ++w){
    float o3 = p.b3[0];
    #pragma unroll
    for(int o=0;o<4;o++){
      float s = p.b2[o];
      #pragma unroll
      for(int r=0;r<3;r++)
        #pragma unroll
        for(int kk=0;kk<5;kk++){
          int c = w - 2 + kk;
          float v = (c>=0 && c<=101) ? xr[r*116 + 1 + (c<0?0:(c>101?101:c))] : 0.f;
          s += v*p.W2[o*15 + r*5 + kk];
        }
      float nv = (s - m2)*rs2*p.g2[o*102+w] + p.be2[o*102+w];
      o3 += fmaxf(nv, 0.f)*p.W3[o];
    }
    s31 += o3; s32 += o3*o3;
    my[w] = o3;
  }
  float m3  = s31*(1.f/102.f);
  float rs3 = frsq(s32*(1.f/102.f) - m3*m3 + 1e-5f);
  float a1[32];
  #pragma unroll
  for(int j=0;j<32;j++) a1[j] = p.b1f[j];
  for(int w=0; w<102; ++w){
    float v = fmaxf((my[w]-m3)*rs3*p.g3[w] + p.be3[w], 0.f);
    #pragma unroll
    for(int j=0;j<32;j++) a1[j] += v*p.W1f[j*108+w];
  }
  #pragma unroll
  for(int d=0;d<3;d++)
    #pragma unroll
    for(int j=0;j<32;j++){
      a1[j] += pp[d]*p.W1f[j*108+102+d];
      a1[j] += vel[d]*p.W1f[j*108+105+d];
    }
  {
    float s=0.f,qq=0.f;
    #pragma unroll
    for(int j=0;j<32;j++){ s+=a1[j]; qq+=a1[j]*a1[j]; }
    float m=s*(1.f/32.f), rs=frsq(qq*(1.f/32.f)-m*m+1e-5f);
    #pragma unroll
    for(int j=0;j<32;j++) a1[j]=fmaxf((a1[j]-m)*rs*p.g1f[j]+p.be1f[j],0.f);
  }
  float a2[32];
  #pragma unroll
  for(int j=0;j<32;j++){
    float a = p.b2f[j];
    #pragma unroll
    for(int k=0;k<32;k++) a += a1[k]*p.W2f[j*32+k];
    a2[j]=a;
  }
  {
    float s=0.f,qq=0.f;
    #pragma unroll
    for(int j=0;j<32;j++){ s+=a2[j]; qq+=a2[j]*a2[j]; }
    float m=s*(1.f/32.f), rs=frsq(qq*(1.f/32.f)-m*m+1e-5f);
    #pragma unroll
    for(int j=0;j<32;j++) a2[j]=fmaxf((a2[j]-m)*rs*p.g2f[j]+p.be2f[j],0.f);
  }
  float t1=0.f,t2=0.f;
  for(int w=0;w<102;++w){
    float a = p.b3f[w];
    #pragma unroll
    for(int j=0;j<32;j++) a += a2[j]*p.W3f[w*32+j];
    t1+=a; t2+=a*a;
    my[w]=a;
  }
  float mf=t1*(1.f/102.f), rsf=frsq(t2*(1.f/102.f)-mf*mf+1e-5f);
  for(int w=0;w<102;++w) my[w]=sigmf((my[w]-mf)*rsf*p.g3f[w]+p.be3f[w]);
  __syncthreads();
  float* op = p.out + (size_t)blockIdx.x*13056;
  #pragma unroll 1
  for(int m=0;m<26;m++){
    int i4 = tid + 128*m;
    if(i4 < 3264){
      int i0=i4*4;
      float4 v;
      #pragma unroll
      for(int ee=0;ee<4;ee++){
        int idx=i0+ee; int sm=idx/102; int wd=idx-sm*102;
        ((float*)&v)[ee]=sbuf[sm*103+wd];
      }
      *reinterpret_cast<float4*>(op+i0)=v;
    }
  }
}

extern "C" void kernel_launch(void* const* d_in, const int* in_sizes, int n_in,
                              void* d_out, int out_size, void* d_ws, size_t ws_size,
                              hipStream_t stream) {
  (void)in_sizes; (void)n_in; (void)out_size;
  Params p;
  p.x    = (const float*)d_in[0];
  p.Wih0 = (const float*)d_in[1];  p.Whh0 = (const float*)d_in[2];
  p.bih0 = (const float*)d_in[3];  p.bhh0 = (const float*)d_in[4];
  p.Wih1 = (const float*)d_in[5];  p.Whh1 = (const float*)d_in[6];
  p.bih1 = (const float*)d_in[7];  p.bhh1 = (const float*)d_in[8];
  p.fcW  = (const float*)d_in[9];  p.fcb  = (const float*)d_in[10];
  p.W2   = (const float*)d_in[11]; p.b2   = (const float*)d_in[12];
  p.g2   = (const float*)d_in[13]; p.be2  = (const float*)d_in[14];
  p.W3   = (const float*)d_in[15]; p.b3   = (const float*)d_in[16];
  p.g3   = (const float*)d_in[17]; p.be3  = (const float*)d_in[18];
  p.W1f  = (const float*)d_in[19]; p.b1f  = (const float*)d_in[20];
  p.g1f  = (const float*)d_in[21]; p.be1f = (const float*)d_in[22];
  p.W2f  = (const float*)d_in[23]; p.b2f  = (const float*)d_in[24];
  p.g2f  = (const float*)d_in[25]; p.be2f = (const float*)d_in[26];
  p.W3f  = (const float*)d_in[27]; p.b3f  = (const float*)d_in[28];
  p.g3f  = (const float*)d_in[29]; p.be3f = (const float*)d_in[30];
  p.out  = (float*)d_out;

  // ws layout (floats): pv[6*N] | bsum[256] | ptail[1518] | frags (u16)
  const size_t PV_F   = (size_t)6*NSAMP;
  const size_t BS_F   = 256;
  const size_t FRAG_BYTES = (size_t)NFRAG*64*8*2;
  const size_t head_f = PV_F + BS_F + PT_N;
  const size_t need = head_f*4 + FRAG_BYTES;

  if(ws_size >= need){
    float* pv    = (float*)d_ws;
    float* bsum  = pv + PV_F;
    float* ptail = bsum + BS_F;
    unsigned short* frags = (unsigned short*)(ptail + PT_N);
    p.pv = pv; p.ptail = ptail; p.frags = frags;
    prep_kernel<<<1, 256, 0, stream>>>(p, frags, bsum, ptail);
    lstm_kernel<<<NSAMP/64, 256, 0, stream>>>(p.x, frags, bsum, p.fcW, p.fcb, pv);
    tail_kernel<<<NSAMP/64, 256, 0, stream>>>(p);
  } else {
    p.pv = nullptr; p.ptail = nullptr; p.frags = nullptr;
    csnet_mono<<<NSAMP/128, 128, 0, stream>>>(p);
  }
}